// Round 1
// baseline (434.190 us; speedup 1.0000x reference)
//
#include <hip/hip_runtime.h>
#include <math.h>

#define BB 2
#define TT 2048
#define DD 1024
#define HH 16
#define INNERD 512
#define FFD 4096
#define NPROJ 2560     // D + 3*INNER
#define CATD 3072      // 3*D
#define MROWS (BB*TT)  // 4096
#define CHUNK 64
#define NCH (TT/CHUNK) // 32
#define BH 32          // B*H

typedef __bf16 bf16;
typedef __attribute__((ext_vector_type(8))) __bf16 bf16x8;
typedef __attribute__((ext_vector_type(4))) __bf16 bf16x4;
typedef __attribute__((ext_vector_type(4))) float f32x4;

struct Part4 { void* p0; void* p1; void* p2; void* p3; };

// ---------------------------------------------------------------- fused prep:
// blocks [0,4096): LN1 row kernel
// blocks [4096,18432): 32x32 transpose tiles for the 5 weights
__global__ __launch_bounds__(256) void prep_fused(
    const float* __restrict__ inputs, const float* __restrict__ ln1_g,
    const float* __restrict__ ln1_b, bf16* __restrict__ normed,
    const float* __restrict__ W_in,  bf16* __restrict__ wt_in,
    const float* __restrict__ W_c,   bf16* __restrict__ wt_c,
    const float* __restrict__ W_mix, bf16* __restrict__ wt_mix,
    const float* __restrict__ W1,    bf16* __restrict__ wt1,
    const float* __restrict__ W2,    bf16* __restrict__ wt2)
{
    int blk = blockIdx.x, tid = threadIdx.x;
    if (blk < MROWS) {
        // ---- LN1 ----
        int row = blk;
        f32x4 xv = ((const f32x4*)(inputs + (size_t)row * DD))[tid];
        float s = xv[0] + xv[1] + xv[2] + xv[3];
        float s2 = xv[0]*xv[0] + xv[1]*xv[1] + xv[2]*xv[2] + xv[3]*xv[3];
        #pragma unroll
        for (int off = 32; off > 0; off >>= 1) {
            s  += __shfl_xor(s,  off, 64);
            s2 += __shfl_xor(s2, off, 64);
        }
        __shared__ float rs[4], rs2[4];
        int wid = tid >> 6;
        if ((tid & 63) == 0) { rs[wid] = s; rs2[wid] = s2; }
        __syncthreads();
        s  = rs[0] + rs[1] + rs[2] + rs[3];
        s2 = rs2[0] + rs2[1] + rs2[2] + rs2[3];
        float mean = s * (1.0f / DD);
        float var  = s2 * (1.0f / DD) - mean * mean;
        float rstd = rsqrtf(var + 1e-5f);
        f32x4 gv = ((const f32x4*)ln1_g)[tid];
        f32x4 bv = ((const f32x4*)ln1_b)[tid];
        bf16x4 o;
        #pragma unroll
        for (int q = 0; q < 4; q++)
            o[q] = (bf16)((xv[q] - mean) * rstd * gv[q] + bv[q]);
        ((bf16x4*)(normed + (size_t)row * DD))[tid] = o;
        return;
    }
    // ---- transpose fp32(K,N) -> bf16(N,K), 32x32 tiles ----
    int tb = blk - MROWS;
    const float* W; bf16* Wt; int Kd, Nd;
    if      (tb < 2560)  {             W = W_in;  Wt = wt_in;  Kd = 1024; Nd = 2560; }
    else if (tb < 3072)  { tb -= 2560; W = W_c;   Wt = wt_c;   Kd = 512;  Nd = 1024; }
    else if (tb < 6144)  { tb -= 3072; W = W_mix; Wt = wt_mix; Kd = 3072; Nd = 1024; }
    else if (tb < 10240) { tb -= 6144; W = W1;    Wt = wt1;    Kd = 1024; Nd = 4096; }
    else                 { tb -= 10240;W = W2;    Wt = wt2;    Kd = 4096; Nd = 1024; }
    int ntx = Nd >> 5;
    int nb = (tb % ntx) * 32, kb = (tb / ntx) * 32;
    __shared__ float t[32][33];
    int tx = tid & 31, ty = tid >> 5;   // 32 x 8
    #pragma unroll
    for (int r = 0; r < 32; r += 8)
        t[ty + r][tx] = W[(size_t)(kb + ty + r) * Nd + nb + tx];
    __syncthreads();
    #pragma unroll
    for (int r = 0; r < 32; r += 8)
        Wt[(size_t)(nb + ty + r) * Kd + kb + tx] = (bf16)t[tx][ty + r];
}

// ---------------------------------------------------------------- 256x256 8-phase MFMA GEMM
// BM=BN=256, BK=64, 8 waves (2Mx4N), 512 threads, 128 KiB LDS double-buffer.
// T2 st_16x32 swizzle (linear LDS dest + pre-swizzled global src, swizzled read),
// T3/T4 4 phases per K-tile with counted vmcnt(2), T5 setprio around MFMA cluster.
//
// LDS layout per 32KB buffer (A or B): 256 rows x 64 k bf16, element offset
//   off = row*64 + col, swizzled: off ^= ((row>>2)&1)<<4.
// Staging is linear (global_load_lds writes base+lane*16); the global source
// address is permuted so LDS[linear] holds the swizzled element:
//   lane l of wave-chunk at rows R..R+7 loads row R+(l>>3),
//   col = ((l&7)*8) ^ (l>=32 ? 16 : 0).
__device__ __forceinline__ void stage_half(
    const bf16* __restrict__ src, int ld, int k0, int h_row0,
    bf16* lds_half, int wave, int rl, int ce)
{
    #pragma unroll
    for (int i = 0; i < 2; i++) {
        int R = h_row0 + (i * 8 + wave) * 8 + rl;
        const bf16* g = src + (size_t)R * ld + k0 + ce;
        __builtin_amdgcn_global_load_lds(
            (const __attribute__((address_space(1))) void*)g,
            (__attribute__((address_space(3))) void*)(lds_half + (i * 8 + wave) * 512),
            16, 0, 0);
    }
}

__device__ __forceinline__ bf16x8 frag_ld(const bf16* buf, int row, int col)
{
    int off = row * 64 + col;
    off ^= ((row >> 2) & 1) << 4;          // st_16x32 swizzle (element units)
    return *(const bf16x8*)(buf + off);
}

// EPI 0: +bias -> bf16 Cb    EPI 1: fast-gelu(+bias) -> bf16 Cb
// EPI 4: bf16 partial -> part.p[z] (ldc=DD)
template<int EPI>
__global__ __launch_bounds__(512) void gemm256(
    const bf16* __restrict__ A,  int lda,
    const bf16* __restrict__ Bt, int ldb,
    const float* __restrict__ bias,
    bf16* __restrict__ Cb, int ldc,
    int K, Part4 part)
{
    __shared__ bf16 sA0[16384], sB0[16384], sA1[16384], sB1[16384];  // 128 KiB
    const int tid  = threadIdx.x;
    const int wave = tid >> 6, lane = tid & 63;
    const int m0 = blockIdx.x * 256, n0 = blockIdx.y * 256;
    A  += (size_t)m0 * lda + (size_t)blockIdx.z * K;
    Bt += (size_t)n0 * ldb + (size_t)blockIdx.z * K;
    const int wr = wave >> 2, wc = wave & 3;      // 2 x 4 wave grid
    const int rl = lane >> 3;                                  // staging row-in-8
    const int ce = ((lane & 7) * 8) ^ ((lane >= 32) ? 16 : 0); // pre-swizzled col
    const int fm = lane & 15;                                  // fragment row
    const int fk = (lane >> 4) * 8;                            // fragment k offset

    f32x4 acc[8][4];
    #pragma unroll
    for (int i = 0; i < 8; i++)
        #pragma unroll
        for (int j = 0; j < 4; j++)
            acc[i][j] = (f32x4){0.f, 0.f, 0.f, 0.f};

    const int NT = K >> 6;
    // ---- prologue: tile 0 fully (4 half-tiles), tile 1 A-half0 ----
    stage_half(A,  lda, 0, 0,   sA0,        wave, rl, ce);
    stage_half(A,  lda, 0, 128, sA0 + 8192, wave, rl, ce);
    stage_half(Bt, ldb, 0, 0,   sB0,        wave, rl, ce);
    stage_half(Bt, ldb, 0, 128, sB0 + 8192, wave, rl, ce);
    if (NT > 1) {
        stage_half(A, lda, 64, 0, sA1, wave, rl, ce);
        asm volatile("s_waitcnt vmcnt(2)" ::: "memory");   // tile0 landed, 2 in flight
    } else {
        asm volatile("s_waitcnt vmcnt(0)" ::: "memory");
    }
    __builtin_amdgcn_s_barrier();

    for (int t = 0; t < NT; t++) {
        bf16* Ac = (t & 1) ? sA1 : sA0;
        bf16* Bc = (t & 1) ? sB1 : sB0;
        bf16* An = (t & 1) ? sA0 : sA1;
        bf16* Bn = (t & 1) ? sB0 : sB1;
        const int kn = (t + 1) << 6;
        bf16x8 bq[4][2];
        #pragma unroll
        for (int p = 0; p < 4; p++) {
            bf16x8 aq[2][2];
            if (p == 0) {
                #pragma unroll
                for (int j = 0; j < 4; j++)
                    #pragma unroll
                    for (int ks = 0; ks < 2; ks++)
                        bq[j][ks] = frag_ld(Bc, wc * 64 + j * 16 + fm, ks * 32 + fk);
            }
            #pragma unroll
            for (int ii = 0; ii < 2; ii++)
                #pragma unroll
                for (int ks = 0; ks < 2; ks++)
                    aq[ii][ks] = frag_ld(Ac, wr * 128 + (p * 2 + ii) * 16 + fm,
                                         ks * 32 + fk);
            // stage one half-tile of tile t+1 per phase (A-h0 was staged at the
            // end of the previous iteration, after all reads of that buffer)
            if (t + 1 < NT) {
                if (p == 0) stage_half(A,  lda, kn, 128, An + 8192, wave, rl, ce);
                if (p == 1) stage_half(Bt, ldb, kn, 0,   Bn,        wave, rl, ce);
                if (p == 2) stage_half(Bt, ldb, kn, 128, Bn + 8192, wave, rl, ce);
            }
            __builtin_amdgcn_s_barrier();
            asm volatile("s_waitcnt lgkmcnt(0)" ::: "memory");
            __builtin_amdgcn_sched_barrier(0);
            __builtin_amdgcn_s_setprio(1);
            #pragma unroll
            for (int ii = 0; ii < 2; ii++)
                #pragma unroll
                for (int j = 0; j < 4; j++)
                    #pragma unroll
                    for (int ks = 0; ks < 2; ks++)
                        acc[p * 2 + ii][j] = __builtin_amdgcn_mfma_f32_16x16x32_bf16(
                            aq[ii][ks], bq[j][ks], acc[p * 2 + ii][j], 0, 0, 0);
            __builtin_amdgcn_s_setprio(0);
            __builtin_amdgcn_s_barrier();
        }
        // buffer Ac/Bc fully consumed (phase-3 lgkmcnt + barrier) -> safe to
        // start overwriting with tile t+2's A-half0.
        if (t + 2 < NT)
            stage_half(A, lda, (t + 2) << 6, 0, Ac, wave, rl, ce);
        if (t + 1 < NT) {
            if (t + 2 < NT) asm volatile("s_waitcnt vmcnt(2)" ::: "memory");
            else            asm volatile("s_waitcnt vmcnt(0)" ::: "memory");
            __builtin_amdgcn_s_barrier();
        }
    }

    void* psel = nullptr;
    if constexpr (EPI == 4) {
        int z = blockIdx.z;
        psel = (z == 0) ? part.p0 : (z == 1) ? part.p1 : (z == 2) ? part.p2 : part.p3;
    }

    #pragma unroll
    for (int i = 0; i < 8; i++) {
        int mbase = m0 + wr * 128 + i * 16 + (lane >> 4) * 4;
        #pragma unroll
        for (int j = 0; j < 4; j++) {
            int col = n0 + wc * 64 + j * 16 + fm;
            float bv = 0.f;
            if constexpr (EPI == 0 || EPI == 1) bv = bias[col];
            #pragma unroll
            for (int r = 0; r < 4; r++) {
                int row = mbase + r;
                float v = acc[i][j][r] + bv;
                if constexpr (EPI == 0) {
                    Cb[(size_t)row * ldc + col] = (bf16)v;
                } else if constexpr (EPI == 1) {
                    // fast gelu: x * sigmoid(1.5957691x + 0.07135502x^3)
                    float z2 = v * (1.5957691f + 0.07135502f * v * v);
                    v = v / (1.0f + __expf(-z2));
                    Cb[(size_t)row * ldc + col] = (bf16)v;
                } else {
                    ((bf16*)psel)[(size_t)row * DD + col] = (bf16)v;
                }
            }
        }
    }
}

// ---------------------------------------------------------------- epilogue: cat[:,0:D] = bf16(P0 + P1 + b_c)
__global__ __launch_bounds__(256) void epi_wc(
    const bf16* __restrict__ P0, const bf16* __restrict__ P1,
    const float* __restrict__ bias, bf16* __restrict__ cat)
{
    int id = blockIdx.x * 256 + threadIdx.x;    // over MROWS*DD/4
    int row = id >> 8, cg = id & 255;
    bf16x4 s0 = ((const bf16x4*)P0)[id];
    bf16x4 s1 = ((const bf16x4*)P1)[id];
    f32x4 b  = ((const f32x4*)bias)[cg];
    bf16x4 o;
    #pragma unroll
    for (int q = 0; q < 4; q++) o[q] = (bf16)((float)s0[q] + (float)s1[q] + b[q]);
    *(bf16x4*)(cat + (size_t)row * CATD + cg * 4) = o;
}

// ---------------------------------------------------------------- fused epilogue: W_mix (3 bf16 partials) gate + residual + mask, then LN2
__global__ __launch_bounds__(256) void epi_mix_ln2(
    const bf16* __restrict__ P0, const bf16* __restrict__ P1,
    const bf16* __restrict__ P2, const float* __restrict__ bias,
    const bf16* __restrict__ proj, const float* __restrict__ res,
    const float* __restrict__ mask,
    const float* __restrict__ g2, const float* __restrict__ b2v,
    float* __restrict__ out1, bf16* __restrict__ hbuf)
{
    int row = blockIdx.x, tid = threadIdx.x;
    float m = mask[row];
    size_t off = (size_t)row * DD + tid * 4;
    bf16x4 s0 = *(const bf16x4*)(P0 + off);
    bf16x4 s1 = *(const bf16x4*)(P1 + off);
    bf16x4 s2v = *(const bf16x4*)(P2 + off);
    f32x4 bv = ((const f32x4*)bias)[tid];
    bf16x4 g4 = *(const bf16x4*)(proj + (size_t)row * NPROJ + tid * 4);
    f32x4 rv = ((const f32x4*)(res + (size_t)row * DD))[tid];
    f32x4 v;
    #pragma unroll
    for (int q = 0; q < 4; q++) {
        float sg = 1.0f / (1.0f + __expf(-(float)g4[q]));
        float sv = (float)s0[q] + (float)s1[q] + (float)s2v[q] + bv[q];
        v[q] = (rv[q] + sg * sv) * m;
    }
    ((f32x4*)(out1 + (size_t)row * DD))[tid] = v;
    // LN2
    float s = v[0] + v[1] + v[2] + v[3];
    float s2 = v[0]*v[0] + v[1]*v[1] + v[2]*v[2] + v[3]*v[3];
    #pragma unroll
    for (int off2 = 32; off2 > 0; off2 >>= 1) {
        s  += __shfl_xor(s,  off2, 64);
        s2 += __shfl_xor(s2, off2, 64);
    }
    __shared__ float rs[4], rs2[4];
    int wid = tid >> 6;
    if ((tid & 63) == 0) { rs[wid] = s; rs2[wid] = s2; }
    __syncthreads();
    s  = rs[0] + rs[1] + rs[2] + rs[3];
    s2 = rs2[0] + rs2[1] + rs2[2] + rs2[3];
    float mean = s * (1.0f / DD);
    float var  = s2 * (1.0f / DD) - mean * mean;
    float rstd = rsqrtf(var + 1e-5f);
    f32x4 gg = ((const f32x4*)g2)[tid];
    f32x4 bb = ((const f32x4*)b2v)[tid];
    bf16x4 h;
    #pragma unroll
    for (int q = 0; q < 4; q++)
        h[q] = (bf16)((v[q] - mean) * rstd * gg[q] + bb[q]);
    ((bf16x4*)(hbuf + (size_t)row * DD))[tid] = h;
}

// ---------------------------------------------------------------- final epilogue: out = (out1 + sum 4 bf16 partials + b2) * mask
__global__ __launch_bounds__(256) void epi_w2(
    float* __restrict__ d_out, const float* __restrict__ out1,
    const bf16* __restrict__ P0, const bf16* __restrict__ P1,
    const bf16* __restrict__ P2, const bf16* __restrict__ P3,
    const float* __restrict__ bias, const float* __restrict__ mask)
{
    int id = blockIdx.x * 256 + threadIdx.x;    // over MROWS*DD/4
    int row = id >> 8;                          // 256 f32x4 per row
    float m = mask[row];
    bf16x4 a0 = ((const bf16x4*)P0)[id];
    bf16x4 a1 = ((const bf16x4*)P1)[id];
    bf16x4 a2 = ((const bf16x4*)P2)[id];
    bf16x4 a3 = ((const bf16x4*)P3)[id];
    f32x4 r = ((const f32x4*)out1)[id];
    f32x4 b = ((const f32x4*)bias)[id & 255];
    f32x4 o;
    #pragma unroll
    for (int q = 0; q < 4; q++) {
        float sv = (float)a0[q] + (float)a1[q] + (float)a2[q] + (float)a3[q];
        o[q] = (r[q] + sv + b[q]) * m;
    }
    ((f32x4*)d_out)[id] = o;
}

// ---------------------------------------------------------------- attention helpers
__device__ __forceinline__ float phi_f(float x) {
    return x > 0.f ? x + 1.f : __expf(x);   // elu(x)+1
}

// ---------------------------------------------------------------- mid fused:
// blocks [0,1024): dwconv (both kernels, 2 rows/thread, vectorized)
// blocks [1024,1536): attn phase A local sums — waves 0,1 each own one chunk
// (wave-synchronous LDS, no barrier; waves 2,3 exit)
__global__ __launch_bounds__(256) void mid_fused(
    const bf16* __restrict__ x,
    const float* __restrict__ w_t, const float* __restrict__ b_t,
    const float* __restrict__ w_p, const float* __restrict__ b_p,
    bf16* __restrict__ cat,
    const bf16* __restrict__ proj, const float* __restrict__ mask,
    float* __restrict__ kvsum, float* __restrict__ kssum)
{
    __shared__ float s_ks[2][CHUNK][32], s_vs[2][CHUNK][32];   // 32 KB
    int blk = blockIdx.x, tid = threadIdx.x;
    if (blk < 1024) {
        // ---- dwconv ----
        int id = blk * 256 + tid;                // over (MROWS/2)*128
        int cg = id & 127, rp = id >> 7;
        int c0 = cg * 8;
        int row0 = rp * 2;
        int t0 = row0 & (TT - 1);
        bf16x8 xw[16];
        #pragma unroll
        for (int j = 0; j < 16; j++) {
            int t = t0 - 14 + j;
            if (t >= 0)
                xw[j] = *(const bf16x8*)(x + (size_t)(row0 - 14 + j) * DD + c0);
            else
                #pragma unroll
                for (int q = 0; q < 8; q++) xw[j][q] = (bf16)0.f;
        }
        float y15[2][8], y3[2][8];
        #pragma unroll
        for (int q = 0; q < 8; q++) {
            float bp = b_p[c0 + q], bt = b_t[c0 + q];
            y15[0][q] = bp; y15[1][q] = bp;
            y3[0][q] = bt;  y3[1][q] = bt;
        }
        #pragma unroll
        for (int i = 0; i < 15; i++) {
            float wp[8];
            #pragma unroll
            for (int q = 0; q < 8; q++) wp[q] = w_p[(c0 + q) * 15 + i];
            #pragma unroll
            for (int rr = 0; rr < 2; rr++)
                #pragma unroll
                for (int q = 0; q < 8; q++)
                    y15[rr][q] = fmaf(wp[q], (float)xw[rr + i][q], y15[rr][q]);
        }
        #pragma unroll
        for (int i = 0; i < 3; i++) {
            float wt[8];
            #pragma unroll
            for (int q = 0; q < 8; q++) wt[q] = w_t[(c0 + q) * 3 + i];
            #pragma unroll
            for (int rr = 0; rr < 2; rr++)
                #pragma unroll
                for (int q = 0; q < 8; q++)
                    y3[rr][q] = fmaf(wt[q], (float)xw[rr + 12 + i][q], y3[rr][q]);
        }
        #pragma unroll
        for (int rr = 0; rr < 2; rr++) {
            bf16x8 o3, o15;
            #pragma unroll
            for (int q = 0; q < 8; q++) { o3[q] = (bf16)y3[rr][q]; o15[q] = (bf16)y15[rr][q]; }
            *(bf16x8*)(cat + (size_t)(row0 + rr) * CATD + DD + c0)     = o3;
            *(bf16x8*)(cat + (size_t)(row0 + rr) * CATD + 2 * DD + c0) = o15;
        }
        return;
    }
    // ---- attn phase A ----
    int w = tid >> 6;
    if (w >= 2) return;
    int lane = tid & 63;
    int ci = (blk - 1024) * 2 + w;     // chunk id 0..1023 == bh*NCH + c
    int c  = ci & (NCH - 1);
    int bh = ci >> 5;
    int b  = bh >> 4, hh = bh & (HH - 1);
    float (*ks)[32] = s_ks[w];
    float (*vs)[32] = s_vs[w];
    int row0 = b * TT + c * CHUNK;
    {
        int row = row0 + lane;
        float m = mask[row];
        const bf16* kp = proj + (size_t)row * NPROJ + DD + INNERD + hh * 32;
        const bf16* vp = kp + INNERD;
        #pragma unroll
        for (int s = 0; s < 4; s++) {
            bf16x8 k8 = *(const bf16x8*)(kp + s * 8);
            bf16x8 v8 = *(const bf16x8*)(vp + s * 8);
            #pragma unroll
            for (int q = 0; q < 8; q++) {
                ks[lane][s * 8 + q] = phi_f((float)k8[q]) * m;
                vs[lane][s * 8 + q] = (float)v8[q] * m;
            }
        }
    }
    // wave-synchronous: same wave wrote, same wave reads — compiler inserts lgkmcnt
    int e = lane & 31, d0 = (lane >> 5) * 16;
    float kv[16], ksl[16];
    #pragma unroll
    for (int j = 0; j < 16; j++) { kv[j] = 0.f; ksl[j] = 0.f; }
    for (int t = 0; t < CHUNK; t++) {
        float ve = vs[t][e];
        f32x4 kr[4];
        #pragma unroll
        for (int s = 0; s < 4; s++) kr[s] = *(const f32x4*)&ks[t][d0 + s * 4];
        #pragma unroll
        for (int j = 0; j < 16; j++) {
            float kval = kr[j >> 2][j & 3];
            kv[j] = fmaf(kval, ve, kv[j]);
            ksl[j] += kval;
        }
    }
    size_t base = (size_t)ci * 1024;
    #pragma unroll
    for (int j = 0; j < 16; j++)
        kvsum[base + (size_t)(d0 + j) * 32 + e] = kv[j];
    if (e == 0) {
        #pragma unroll
        for (int j = 0; j < 16; j++)
            kssum[ci * 32 + d0 + j] = ksl[j];
    }
}

// Phase B: exclusive prefix over chunks, per (b,h).
__global__ __launch_bounds__(256) void attn_prefix(
    const float* __restrict__ kvsum, const float* __restrict__ kssum,
    float* __restrict__ kvpref, float* __restrict__ kspref)
{
    int bh = blockIdx.x;
    int tid = threadIdx.x;
    float run[4] = {0.f, 0.f, 0.f, 0.f};
    for (int c = 0; c < NCH; c++) {
        size_t base = (size_t)(bh * NCH + c) * 1024 + tid * 4;
        #pragma unroll
        for (int q = 0; q < 4; q++) {
            kvpref[base + q] = run[q];
            run[q] += kvsum[base + q];
        }
    }
    if (tid < 32) {
        float r = 0.f;
        for (int c = 0; c < NCH; c++) {
            kspref[(bh * NCH + c) * 32 + tid] = r;
            r += kssum[(bh * NCH + c) * 32 + tid];
        }
    }
}

// Phase C: in-chunk scan, LDS-resident.
__global__ __launch_bounds__(64) void attn_scan(
    const bf16* __restrict__ proj, const float* __restrict__ mask,
    const float* __restrict__ kvpref, const float* __restrict__ kspref,
    bf16* __restrict__ attn_out)
{
    int blk = blockIdx.x;
    int c  = blk & (NCH - 1);
    int bh = blk >> 5;
    int b  = bh >> 4, hh = bh & (HH - 1);
    int lane = threadIdx.x;
    __shared__ float qs[CHUNK][32], ks[CHUNK][32], vs[CHUNK][32];
    __shared__ float ms[CHUNK];
    int row0 = b * TT + c * CHUNK;
    {
        int row = row0 + lane;
        float m = mask[row];
        ms[lane] = m;
        const bf16* qp = proj + (size_t)row * NPROJ + DD + hh * 32;
        const bf16* kp = qp + INNERD;
        const bf16* vp = kp + INNERD;
        #pragma unroll
        for (int s = 0; s < 4; s++) {
            bf16x8 q8 = *(const bf16x8*)(qp + s * 8);
            bf16x8 k8 = *(const bf16x8*)(kp + s * 8);
            bf16x8 v8 = *(const bf16x8*)(vp + s * 8);
            #pragma unroll
            for (int q = 0; q < 8; q++) {
                qs[lane][s * 8 + q] = phi_f((float)q8[q]) * m;
                ks[lane][s * 8 + q] = phi_f((float)k8[q]) * m;
                vs[lane][s * 8 + q] = (float)v8[q] * m;
            }
        }
    }
    int e = lane & 31, d0 = (lane >> 5) * 16;
    float kv[16], ksl[16];
    size_t base = (size_t)blk * 1024;
    #pragma unroll
    for (int j = 0; j < 16; j++) kv[j] = kvpref[base + (size_t)(d0 + j) * 32 + e];
    #pragma unroll
    for (int j = 0; j < 16; j++) ksl[j] = kspref[blk * 32 + d0 + j];
    __syncthreads();
    for (int t = 0; t < CHUNK; t++) {
        float ve = vs[t][e];
        f32x4 kr[4], qr[4];
        #pragma unroll
        for (int s = 0; s < 4; s++) kr[s] = *(const f32x4*)&ks[t][d0 + s * 4];
        #pragma unroll
        for (int s = 0; s < 4; s++) qr[s] = *(const f32x4*)&qs[t][d0 + s * 4];
        float num0 = 0.f, num1 = 0.f, den0 = 0.f, den1 = 0.f;
        #pragma unroll
        for (int j = 0; j < 16; j++) {
            float kval = kr[j >> 2][j & 3], qval = qr[j >> 2][j & 3];
            kv[j]  = fmaf(kval, ve, kv[j]);   // inclusive cumsum
            ksl[j] += kval;
            if (j & 1) { num1 = fmaf(qval, kv[j], num1); den1 = fmaf(qval, ksl[j], den1); }
            else       { num0 = fmaf(qval, kv[j], num0); den0 = fmaf(qval, ksl[j], den0); }
        }
        float num = num0 + num1, den = den0 + den1;
        num += __shfl_xor(num, 32, 64);
        den += __shfl_xor(den, 32, 64);
        if (lane < 32)
            attn_out[(size_t)(row0 + t) * INNERD + hh * 32 + e] =
                (bf16)(num / (den + 1e-6f) * ms[t]);
    }
}

// ---------------------------------------------------------------- launch
extern "C" void kernel_launch(void* const* d_in, const int* in_sizes, int n_in,
                              void* d_out, int out_size, void* d_ws, size_t ws_size,
                              hipStream_t stream)
{
    const float* inputs = (const float*)d_in[0];
    const float* mask   = (const float*)d_in[1];
    const float* ln1_g  = (const float*)d_in[2];
    const float* ln1_b  = (const float*)d_in[3];
    const float* W_in   = (const float*)d_in[4];
    const float* b_in   = (const float*)d_in[5];
    const float* W_c    = (const float*)d_in[6];
    const float* b_c    = (const float*)d_in[7];
    const float* w_t    = (const float*)d_in[8];
    const float* b_t    = (const float*)d_in[9];
    const float* w_p    = (const float*)d_in[10];
    const float* b_p    = (const float*)d_in[11];
    const float* W_mix  = (const float*)d_in[12];
    const float* b_mix  = (const float*)d_in[13];
    const float* ln2_g  = (const float*)d_in[14];
    const float* ln2_b  = (const float*)d_in[15];
    const float* W1     = (const float*)d_in[16];
    const float* b1     = (const float*)d_in[17];
    const float* W2     = (const float*)d_in[18];
    const float* b2     = (const float*)d_in[19];
    float* out = (float*)d_out;

    // workspace layout (bytes). ffn1 aliases [normed|proj|attnb] (dead by W1).
    // attn kv scratch aliases out1 (dead until epi_mix_ln2).
    // Split-K bf16 partials (non-atomic, fully overwritten by their GEMM):
    //   W_c : d_out, out1-region
    //   W_mix: d_out (2 partials), hbuf-region
    //   W2  : cat-region (3 partials), hbuf-region
    char* p = (char*)d_ws;
    bf16* normed = (bf16*)p;  p += (size_t)MROWS * DD * 2;
    bf16* proj   = (bf16*)p;  p += (size_t)MROWS * NPROJ * 2;
    bf16* attnb  = (bf16*)p;  p += (size_t)MROWS * INNERD * 2;
    bf16* cat    = (bf16*)p;  p += (size_t)MROWS * CATD * 2;
    float* out1  = (float*)p; p += (size_t)MROWS * DD * 4;
    bf16* hbuf   = (bf16*)p;  p += (size_t)MROWS * DD * 2;
    bf16* wt_in  = (bf16*)p;  p += (size_t)NPROJ * DD * 2;
    bf16* wt_c   = (bf16*)p;  p += (size_t)DD * INNERD * 2;
    bf16* wt_mix = (bf16*)p;  p += (size_t)DD * CATD * 2;
    bf16* wt1    = (bf16*)p;  p += (size_t)FFD * DD * 2;
    bf16* wt2    = (bf16*)p;  p += (size_t)DD * FFD * 2;
    bf16* ffn1   = (bf16*)d_ws;                  // alias [normed|proj|attnb]
    float* kvsum = out1;                         // alias out1 region (attn)
    float* kvpref= kvsum  + (size_t)BH * NCH * 1024;
    float* kssum = kvpref + (size_t)BH * NCH * 1024;
    float* kspref= kssum  + (size_t)BH * NCH * 32;
    // split-K bf16 partials
    bf16*  c_p0  = (bf16*)d_out;
    bf16*  c_p1  = (bf16*)out1;
    bf16*  m_p0  = (bf16*)d_out;
    bf16*  m_p1  = (bf16*)d_out + (size_t)MROWS * DD;
    bf16*  m_p2  = hbuf;
    bf16*  w2_p0 = cat;
    bf16*  w2_p1 = cat + (size_t)MROWS * DD;
    bf16*  w2_p2 = cat + (size_t)MROWS * DD * 2;
    bf16*  w2_p3 = hbuf;

    // 1. fused prep: LN1 + all 5 weight transposes (one dispatch)
    prep_fused<<<MROWS + 14336, 256, 0, stream>>>(
        inputs, ln1_g, ln1_b, normed,
        W_in, wt_in, W_c, wt_c, W_mix, wt_mix, W1, wt1, W2, wt2);
    // 2. proj = normed @ W_in + b_in (bf16 out)   grid (M,N)
    gemm256<0><<<dim3(MROWS/256, NPROJ/256), 512, 0, stream>>>(
        normed, DD, wt_in, DD, b_in, proj, NPROJ, DD, Part4{});
    // 3. fused dwconv + attn phase A (one dispatch)
    mid_fused<<<1024 + 512, 256, 0, stream>>>(
        normed, w_t, b_t, w_p, b_p, cat, proj, mask, kvsum, kssum);
    attn_prefix<<<BH, 256, 0, stream>>>(kvsum, kssum, kvpref, kspref);
    attn_scan  <<<BH * NCH, 64, 0, stream>>>(proj, mask, kvpref, kspref, attnb);
    // 5. W_c split-2 bf16 partials, then cat[:,0:D] = bf16(P0+P1+b_c)
    gemm256<4><<<dim3(MROWS/256, DD/256, 2), 512, 0, stream>>>(
        attnb, INNERD, wt_c, INNERD, nullptr, nullptr, DD, INNERD / 2,
        Part4{c_p0, c_p1, nullptr, nullptr});
    epi_wc<<<MROWS * DD / 4 / 256, 256, 0, stream>>>(c_p0, c_p1, b_c, cat);
    // 6. W_mix split-3 bf16 partials
    gemm256<4><<<dim3(MROWS/256, DD/256, 3), 512, 0, stream>>>(
        cat, CATD, wt_mix, CATD, nullptr, nullptr, DD, CATD / 3,
        Part4{m_p0, m_p1, m_p2, nullptr});
    // 7. out1 = (inputs + sigmoid(gate)*(sum P + b_mix))*mask ; hbuf = LN2(out1)
    epi_mix_ln2<<<MROWS, 256, 0, stream>>>(m_p0, m_p1, m_p2, b_mix, proj, inputs,
                                           mask, ln2_g, ln2_b, out1, hbuf);
    // 8. ffn1 = gelu(hbuf @ W1 + b1) (bf16 out; aliases dead normed/proj/attnb)
    gemm256<1><<<dim3(MROWS/256, FFD/256), 512, 0, stream>>>(
        hbuf, DD, wt1, DD, b1, ffn1, FFD, DD, Part4{});
    // 9. W2 split-4 bf16 partials
    gemm256<4><<<dim3(MROWS/256, DD/256, 4), 512, 0, stream>>>(
        ffn1, FFD, wt2, FFD, nullptr, nullptr, DD, FFD / 4,
        Part4{w2_p0, w2_p1, w2_p2, w2_p3});
    // 10. out = (out1 + sum P + b2) * mask
    epi_w2<<<MROWS * DD / 4 / 256, 256, 0, stream>>>(out, out1, w2_p0, w2_p1,
                                                     w2_p2, w2_p3, b2, mask);
}

// Round 2
// 414.722 us; speedup vs baseline: 1.0469x; 1.0469x over previous
//
#include <hip/hip_runtime.h>
#include <math.h>

#define BB 2
#define TT 2048
#define DD 1024
#define HH 16
#define INNERD 512
#define FFD 4096
#define NPROJ 2560     // D + 3*INNER
#define CATD 3072      // 3*D
#define MROWS (BB*TT)  // 4096
#define CHUNK 64
#define NCH (TT/CHUNK) // 32
#define BH 32          // B*H

typedef __bf16 bf16;
typedef __attribute__((ext_vector_type(8))) __bf16 bf16x8;
typedef __attribute__((ext_vector_type(4))) __bf16 bf16x4;
typedef __attribute__((ext_vector_type(4))) float f32x4;

struct Part4 { void* p0; void* p1; void* p2; void* p3; };

// ---------------------------------------------------------------- fused prep:
// blocks [0,4096): LN1 row kernel
// blocks [4096,18432): 32x32 transpose tiles for the 5 weights
__global__ __launch_bounds__(256) void prep_fused(
    const float* __restrict__ inputs, const float* __restrict__ ln1_g,
    const float* __restrict__ ln1_b, bf16* __restrict__ normed,
    const float* __restrict__ W_in,  bf16* __restrict__ wt_in,
    const float* __restrict__ W_c,   bf16* __restrict__ wt_c,
    const float* __restrict__ W_mix, bf16* __restrict__ wt_mix,
    const float* __restrict__ W1,    bf16* __restrict__ wt1,
    const float* __restrict__ W2,    bf16* __restrict__ wt2)
{
    int blk = blockIdx.x, tid = threadIdx.x;
    if (blk < MROWS) {
        // ---- LN1 ----
        int row = blk;
        f32x4 xv = ((const f32x4*)(inputs + (size_t)row * DD))[tid];
        float s = xv[0] + xv[1] + xv[2] + xv[3];
        float s2 = xv[0]*xv[0] + xv[1]*xv[1] + xv[2]*xv[2] + xv[3]*xv[3];
        #pragma unroll
        for (int off = 32; off > 0; off >>= 1) {
            s  += __shfl_xor(s,  off, 64);
            s2 += __shfl_xor(s2, off, 64);
        }
        __shared__ float rs[4], rs2[4];
        int wid = tid >> 6;
        if ((tid & 63) == 0) { rs[wid] = s; rs2[wid] = s2; }
        __syncthreads();
        s  = rs[0] + rs[1] + rs[2] + rs[3];
        s2 = rs2[0] + rs2[1] + rs2[2] + rs2[3];
        float mean = s * (1.0f / DD);
        float var  = s2 * (1.0f / DD) - mean * mean;
        float rstd = rsqrtf(var + 1e-5f);
        f32x4 gv = ((const f32x4*)ln1_g)[tid];
        f32x4 bv = ((const f32x4*)ln1_b)[tid];
        bf16x4 o;
        #pragma unroll
        for (int q = 0; q < 4; q++)
            o[q] = (bf16)((xv[q] - mean) * rstd * gv[q] + bv[q]);
        ((bf16x4*)(normed + (size_t)row * DD))[tid] = o;
        return;
    }
    // ---- transpose fp32(K,N) -> bf16(N,K), 32x32 tiles ----
    int tb = blk - MROWS;
    const float* W; bf16* Wt; int Kd, Nd;
    if      (tb < 2560)  {             W = W_in;  Wt = wt_in;  Kd = 1024; Nd = 2560; }
    else if (tb < 3072)  { tb -= 2560; W = W_c;   Wt = wt_c;   Kd = 512;  Nd = 1024; }
    else if (tb < 6144)  { tb -= 3072; W = W_mix; Wt = wt_mix; Kd = 3072; Nd = 1024; }
    else if (tb < 10240) { tb -= 6144; W = W1;    Wt = wt1;    Kd = 1024; Nd = 4096; }
    else                 { tb -= 10240;W = W2;    Wt = wt2;    Kd = 4096; Nd = 1024; }
    int ntx = Nd >> 5;
    int nb = (tb % ntx) * 32, kb = (tb / ntx) * 32;
    __shared__ float t[32][33];
    int tx = tid & 31, ty = tid >> 5;   // 32 x 8
    #pragma unroll
    for (int r = 0; r < 32; r += 8)
        t[ty + r][tx] = W[(size_t)(kb + ty + r) * Nd + nb + tx];
    __syncthreads();
    #pragma unroll
    for (int r = 0; r < 32; r += 8)
        Wt[(size_t)(nb + ty + r) * Kd + kb + tx] = (bf16)t[tx][ty + r];
}

// ---------------------------------------------------------------- 256x256 MFMA GEMM
// BM=BN=256, BK=32, 8 waves (2Mx4N), 512 threads.
// 4-deep LDS buffer rotation (4 x (16KB A + 16KB B) = 128 KiB): tile t computes
// from buf t&3 while staging tile t+3 into buf (t+3)&3 == buf of tile t-1
// (reads finished one full tile ago -> race-free). Counted-vmcnt ledger
// (4 stage-instrs/wave/tile): tile-end vmcnt(8) => tile t+1 fully landed,
// tiles t+2,t+3 in flight => ~2 K-tiles (~1000 cyc) of load-latency slack.
//
// LDS swizzle (conflict-free ds_read_b128): tile = 256 rows x 32 cols bf16.
// 16-byte slot address for (row r, col-chunk cc in 0..3):
//   slot16(r,cc) = (r>>1)*8 + ( (((r&1)<<2)|cc) ^ ((r>>1)&7) )
// A wave's fragment read (16 consecutive rows, fixed cc) then hits every
// 4-bank set exactly 2x -> free (2-way, m136). global_load_lds keeps a LINEAR
// per-wave LDS dest (base + lane*16); the involution is applied on the global
// SOURCE address instead (both-sides rule): lane l (slot s=l&7, row-pair rp)
// fetches x = s ^ (rp&7); r = rp*2 + ((x>>2)&1); cc = x&3.
__device__ __forceinline__ void stage_tile32(
    const bf16* __restrict__ src, int ld, int k0,
    bf16* lds, int wave, int lane)
{
    #pragma unroll
    for (int i = 0; i < 2; i++) {
        int rp = (i * 8 + wave) * 8 + (lane >> 3);   // row-pair 0..127
        int x  = (lane & 7) ^ (rp & 7);
        int r  = rp * 2 + ((x >> 2) & 1);
        int cc = x & 3;
        const bf16* g = src + (size_t)r * ld + k0 + cc * 8;
        __builtin_amdgcn_global_load_lds(
            (const __attribute__((address_space(1))) void*)g,
            (__attribute__((address_space(3))) void*)(lds + (i * 8 + wave) * 512),
            16, 0, 0);
    }
}

__device__ __forceinline__ bf16x8 frag32(const bf16* buf, int row, int cc)
{
    int off16 = (row >> 1) * 8 + ((((row & 1) << 2) | cc) ^ ((row >> 1) & 7));
    return *(const bf16x8*)(buf + off16 * 8);
}

__device__ __forceinline__ void tile_step(
    int t, int NT, const bf16* __restrict__ A, int lda,
    const bf16* __restrict__ Bt, int ldb,
    const bf16* Acur, const bf16* Bcur, bf16* Ast, bf16* Bst,
    int wave, int lane, int wr, int wc, f32x4 (&acc)[8][4])
{
    const int fm = lane & 15, cc = lane >> 4;
    bf16x8 bq[4], aq[4];
    // ---- phase 0: C rows 0..63 of this wave ----
    #pragma unroll
    for (int j = 0; j < 4; j++) bq[j] = frag32(Bcur, wc * 64 + j * 16 + fm, cc);
    #pragma unroll
    for (int i = 0; i < 4; i++) aq[i] = frag32(Acur, wr * 128 + i * 16 + fm, cc);
    if (t + 3 < NT) stage_tile32(A, lda, (t + 3) * 32, Ast, wave, lane);
    __builtin_amdgcn_s_barrier();
    asm volatile("s_waitcnt lgkmcnt(0)" ::: "memory");
    __builtin_amdgcn_sched_barrier(0);
    __builtin_amdgcn_s_setprio(1);
    #pragma unroll
    for (int i = 0; i < 4; i++)
        #pragma unroll
        for (int j = 0; j < 4; j++)
            acc[i][j] = __builtin_amdgcn_mfma_f32_16x16x32_bf16(
                aq[i], bq[j], acc[i][j], 0, 0, 0);
    __builtin_amdgcn_s_setprio(0);
    __builtin_amdgcn_s_barrier();
    // ---- phase 1: C rows 64..127 of this wave ----
    #pragma unroll
    for (int i = 0; i < 4; i++) aq[i] = frag32(Acur, wr * 128 + (4 + i) * 16 + fm, cc);
    if (t + 3 < NT) stage_tile32(Bt, ldb, (t + 3) * 32, Bst, wave, lane);
    __builtin_amdgcn_s_barrier();
    asm volatile("s_waitcnt lgkmcnt(0)" ::: "memory");
    __builtin_amdgcn_sched_barrier(0);
    __builtin_amdgcn_s_setprio(1);
    #pragma unroll
    for (int i = 0; i < 4; i++)
        #pragma unroll
        for (int j = 0; j < 4; j++)
            acc[4 + i][j] = __builtin_amdgcn_mfma_f32_16x16x32_bf16(
                aq[i], bq[j], acc[4 + i][j], 0, 0, 0);
    __builtin_amdgcn_s_setprio(0);
    __builtin_amdgcn_s_barrier();
    // ---- tile-end: ensure tile t+1 fully landed (counted, never over-drain) ----
    if (t + 1 < NT) {
        if (t + 3 < NT)      asm volatile("s_waitcnt vmcnt(8)" ::: "memory");
        else if (t + 2 < NT) asm volatile("s_waitcnt vmcnt(4)" ::: "memory");
        else                 asm volatile("s_waitcnt vmcnt(0)" ::: "memory");
        __builtin_amdgcn_s_barrier();
    }
}

// EPI 0: +bias -> bf16 Cb    EPI 1: fast-gelu(+bias) -> bf16 Cb
// EPI 4: bf16 partial -> part.p[z] (ldc=DD)
template<int EPI>
__global__ __launch_bounds__(512) void gemm256(
    const bf16* __restrict__ A,  int lda,
    const bf16* __restrict__ Bt, int ldb,
    const float* __restrict__ bias,
    bf16* __restrict__ Cb, int ldc,
    int K, Part4 part)
{
    __shared__ bf16 sA[4][8192], sB[4][8192];   // 128 KiB
    const int tid  = threadIdx.x;
    const int wave = tid >> 6, lane = tid & 63;
    const int m0 = blockIdx.x * 256, n0 = blockIdx.y * 256;
    A  += (size_t)m0 * lda + (size_t)blockIdx.z * K;
    Bt += (size_t)n0 * ldb + (size_t)blockIdx.z * K;
    const int wr = wave >> 2, wc = wave & 3;      // 2 x 4 wave grid
    const int fm = lane & 15;

    f32x4 acc[8][4];
    #pragma unroll
    for (int i = 0; i < 8; i++)
        #pragma unroll
        for (int j = 0; j < 4; j++)
            acc[i][j] = (f32x4){0.f, 0.f, 0.f, 0.f};

    const int NT = K >> 5;                        // K in {256,1024} -> NT in {8,32}
    // ---- prologue: stage tiles 0,1,2 (12 instrs/wave); tile0 landed ----
    stage_tile32(A,  lda, 0,  sA[0], wave, lane);
    stage_tile32(Bt, ldb, 0,  sB[0], wave, lane);
    stage_tile32(A,  lda, 32, sA[1], wave, lane);
    stage_tile32(Bt, ldb, 32, sB[1], wave, lane);
    stage_tile32(A,  lda, 64, sA[2], wave, lane);
    stage_tile32(Bt, ldb, 64, sB[2], wave, lane);
    asm volatile("s_waitcnt vmcnt(8)" ::: "memory");
    __builtin_amdgcn_s_barrier();

    for (int t = 0; t < NT; t += 4) {
        tile_step(t + 0, NT, A, lda, Bt, ldb, sA[0], sB[0], sA[3], sB[3],
                  wave, lane, wr, wc, acc);
        tile_step(t + 1, NT, A, lda, Bt, ldb, sA[1], sB[1], sA[0], sB[0],
                  wave, lane, wr, wc, acc);
        tile_step(t + 2, NT, A, lda, Bt, ldb, sA[2], sB[2], sA[1], sB[1],
                  wave, lane, wr, wc, acc);
        tile_step(t + 3, NT, A, lda, Bt, ldb, sA[3], sB[3], sA[2], sB[2],
                  wave, lane, wr, wc, acc);
    }

    void* psel = nullptr;
    if constexpr (EPI == 4) {
        int z = blockIdx.z;
        psel = (z == 0) ? part.p0 : (z == 1) ? part.p1 : (z == 2) ? part.p2 : part.p3;
    }

    #pragma unroll
    for (int i = 0; i < 8; i++) {
        int mbase = m0 + wr * 128 + i * 16 + (lane >> 4) * 4;
        #pragma unroll
        for (int j = 0; j < 4; j++) {
            int col = n0 + wc * 64 + j * 16 + fm;
            float bv = 0.f;
            if constexpr (EPI == 0 || EPI == 1) bv = bias[col];
            #pragma unroll
            for (int r = 0; r < 4; r++) {
                int row = mbase + r;
                float v = acc[i][j][r] + bv;
                if constexpr (EPI == 0) {
                    Cb[(size_t)row * ldc + col] = (bf16)v;
                } else if constexpr (EPI == 1) {
                    // fast gelu: x * sigmoid(1.5957691x + 0.07135502x^3)
                    float z2 = v * (1.5957691f + 0.07135502f * v * v);
                    v = v / (1.0f + __expf(-z2));
                    Cb[(size_t)row * ldc + col] = (bf16)v;
                } else {
                    ((bf16*)psel)[(size_t)row * DD + col] = (bf16)v;
                }
            }
        }
    }
}

// ---------------------------------------------------------------- epilogue: cat[:,0:D] = bf16(P0 + P1 + b_c)
__global__ __launch_bounds__(256) void epi_wc(
    const bf16* __restrict__ P0, const bf16* __restrict__ P1,
    const float* __restrict__ bias, bf16* __restrict__ cat)
{
    int id = blockIdx.x * 256 + threadIdx.x;    // over MROWS*DD/4
    int row = id >> 8, cg = id & 255;
    bf16x4 s0 = ((const bf16x4*)P0)[id];
    bf16x4 s1 = ((const bf16x4*)P1)[id];
    f32x4 b  = ((const f32x4*)bias)[cg];
    bf16x4 o;
    #pragma unroll
    for (int q = 0; q < 4; q++) o[q] = (bf16)((float)s0[q] + (float)s1[q] + b[q]);
    *(bf16x4*)(cat + (size_t)row * CATD + cg * 4) = o;
}

// ---------------------------------------------------------------- fused epilogue: W_mix (3 bf16 partials) gate + residual + mask, then LN2
__global__ __launch_bounds__(256) void epi_mix_ln2(
    const bf16* __restrict__ P0, const bf16* __restrict__ P1,
    const bf16* __restrict__ P2, const float* __restrict__ bias,
    const bf16* __restrict__ proj, const float* __restrict__ res,
    const float* __restrict__ mask,
    const float* __restrict__ g2, const float* __restrict__ b2v,
    float* __restrict__ out1, bf16* __restrict__ hbuf)
{
    int row = blockIdx.x, tid = threadIdx.x;
    float m = mask[row];
    size_t off = (size_t)row * DD + tid * 4;
    bf16x4 s0 = *(const bf16x4*)(P0 + off);
    bf16x4 s1 = *(const bf16x4*)(P1 + off);
    bf16x4 s2v = *(const bf16x4*)(P2 + off);
    f32x4 bv = ((const f32x4*)bias)[tid];
    bf16x4 g4 = *(const bf16x4*)(proj + (size_t)row * NPROJ + tid * 4);
    f32x4 rv = ((const f32x4*)(res + (size_t)row * DD))[tid];
    f32x4 v;
    #pragma unroll
    for (int q = 0; q < 4; q++) {
        float sg = 1.0f / (1.0f + __expf(-(float)g4[q]));
        float sv = (float)s0[q] + (float)s1[q] + (float)s2v[q] + bv[q];
        v[q] = (rv[q] + sg * sv) * m;
    }
    ((f32x4*)(out1 + (size_t)row * DD))[tid] = v;
    // LN2
    float s = v[0] + v[1] + v[2] + v[3];
    float s2 = v[0]*v[0] + v[1]*v[1] + v[2]*v[2] + v[3]*v[3];
    #pragma unroll
    for (int off2 = 32; off2 > 0; off2 >>= 1) {
        s  += __shfl_xor(s,  off2, 64);
        s2 += __shfl_xor(s2, off2, 64);
    }
    __shared__ float rs[4], rs2[4];
    int wid = tid >> 6;
    if ((tid & 63) == 0) { rs[wid] = s; rs2[wid] = s2; }
    __syncthreads();
    s  = rs[0] + rs[1] + rs[2] + rs[3];
    s2 = rs2[0] + rs2[1] + rs2[2] + rs2[3];
    float mean = s * (1.0f / DD);
    float var  = s2 * (1.0f / DD) - mean * mean;
    float rstd = rsqrtf(var + 1e-5f);
    f32x4 gg = ((const f32x4*)g2)[tid];
    f32x4 bb = ((const f32x4*)b2v)[tid];
    bf16x4 h;
    #pragma unroll
    for (int q = 0; q < 4; q++)
        h[q] = (bf16)((v[q] - mean) * rstd * gg[q] + bb[q]);
    ((bf16x4*)(hbuf + (size_t)row * DD))[tid] = h;
}

// ---------------------------------------------------------------- final epilogue: out = (out1 + sum 4 bf16 partials + b2) * mask
__global__ __launch_bounds__(256) void epi_w2(
    float* __restrict__ d_out, const float* __restrict__ out1,
    const bf16* __restrict__ P0, const bf16* __restrict__ P1,
    const bf16* __restrict__ P2, const bf16* __restrict__ P3,
    const float* __restrict__ bias, const float* __restrict__ mask)
{
    int id = blockIdx.x * 256 + threadIdx.x;    // over MROWS*DD/4
    int row = id >> 8;                          // 256 f32x4 per row
    float m = mask[row];
    bf16x4 a0 = ((const bf16x4*)P0)[id];
    bf16x4 a1 = ((const bf16x4*)P1)[id];
    bf16x4 a2 = ((const bf16x4*)P2)[id];
    bf16x4 a3 = ((const bf16x4*)P3)[id];
    f32x4 r = ((const f32x4*)out1)[id];
    f32x4 b = ((const f32x4*)bias)[id & 255];
    f32x4 o;
    #pragma unroll
    for (int q = 0; q < 4; q++) {
        float sv = (float)a0[q] + (float)a1[q] + (float)a2[q] + (float)a3[q];
        o[q] = (r[q] + sv + b[q]) * m;
    }
    ((f32x4*)d_out)[id] = o;
}

// ---------------------------------------------------------------- attention helpers
__device__ __forceinline__ float phi_f(float x) {
    return x > 0.f ? x + 1.f : __expf(x);   // elu(x)+1
}

// ---------------------------------------------------------------- mid fused:
// blocks [0,1024): dwconv (both kernels, 2 rows/thread, vectorized)
// blocks [1024,1536): attn phase A local sums — waves 0,1 each own one chunk
// (wave-synchronous LDS, no barrier; waves 2,3 exit)
__global__ __launch_bounds__(256) void mid_fused(
    const bf16* __restrict__ x,
    const float* __restrict__ w_t, const float* __restrict__ b_t,
    const float* __restrict__ w_p, const float* __restrict__ b_p,
    bf16* __restrict__ cat,
    const bf16* __restrict__ proj, const float* __restrict__ mask,
    float* __restrict__ kvsum, float* __restrict__ kssum)
{
    __shared__ float s_ks[2][CHUNK][32], s_vs[2][CHUNK][32];   // 32 KB
    int blk = blockIdx.x, tid = threadIdx.x;
    if (blk < 1024) {
        // ---- dwconv ----
        int id = blk * 256 + tid;                // over (MROWS/2)*128
        int cg = id & 127, rp = id >> 7;
        int c0 = cg * 8;
        int row0 = rp * 2;
        int t0 = row0 & (TT - 1);
        bf16x8 xw[16];
        #pragma unroll
        for (int j = 0; j < 16; j++) {
            int t = t0 - 14 + j;
            if (t >= 0)
                xw[j] = *(const bf16x8*)(x + (size_t)(row0 - 14 + j) * DD + c0);
            else
                #pragma unroll
                for (int q = 0; q < 8; q++) xw[j][q] = (bf16)0.f;
        }
        float y15[2][8], y3[2][8];
        #pragma unroll
        for (int q = 0; q < 8; q++) {
            float bp = b_p[c0 + q], bt = b_t[c0 + q];
            y15[0][q] = bp; y15[1][q] = bp;
            y3[0][q] = bt;  y3[1][q] = bt;
        }
        #pragma unroll
        for (int i = 0; i < 15; i++) {
            float wp[8];
            #pragma unroll
            for (int q = 0; q < 8; q++) wp[q] = w_p[(c0 + q) * 15 + i];
            #pragma unroll
            for (int rr = 0; rr < 2; rr++)
                #pragma unroll
                for (int q = 0; q < 8; q++)
                    y15[rr][q] = fmaf(wp[q], (float)xw[rr + i][q], y15[rr][q]);
        }
        #pragma unroll
        for (int i = 0; i < 3; i++) {
            float wt[8];
            #pragma unroll
            for (int q = 0; q < 8; q++) wt[q] = w_t[(c0 + q) * 3 + i];
            #pragma unroll
            for (int rr = 0; rr < 2; rr++)
                #pragma unroll
                for (int q = 0; q < 8; q++)
                    y3[rr][q] = fmaf(wt[q], (float)xw[rr + 12 + i][q], y3[rr][q]);
        }
        #pragma unroll
        for (int rr = 0; rr < 2; rr++) {
            bf16x8 o3, o15;
            #pragma unroll
            for (int q = 0; q < 8; q++) { o3[q] = (bf16)y3[rr][q]; o15[q] = (bf16)y15[rr][q]; }
            *(bf16x8*)(cat + (size_t)(row0 + rr) * CATD + DD + c0)     = o3;
            *(bf16x8*)(cat + (size_t)(row0 + rr) * CATD + 2 * DD + c0) = o15;
        }
        return;
    }
    // ---- attn phase A ----
    int w = tid >> 6;
    if (w >= 2) return;
    int lane = tid & 63;
    int ci = (blk - 1024) * 2 + w;     // chunk id 0..1023 == bh*NCH + c
    int c  = ci & (NCH - 1);
    int bh = ci >> 5;
    int b  = bh >> 4, hh = bh & (HH - 1);
    float (*ks)[32] = s_ks[w];
    float (*vs)[32] = s_vs[w];
    int row0 = b * TT + c * CHUNK;
    {
        int row = row0 + lane;
        float m = mask[row];
        const bf16* kp = proj + (size_t)row * NPROJ + DD + INNERD + hh * 32;
        const bf16* vp = kp + INNERD;
        #pragma unroll
        for (int s = 0; s < 4; s++) {
            bf16x8 k8 = *(const bf16x8*)(kp + s * 8);
            bf16x8 v8 = *(const bf16x8*)(vp + s * 8);
            #pragma unroll
            for (int q = 0; q < 8; q++) {
                ks[lane][s * 8 + q] = phi_f((float)k8[q]) * m;
                vs[lane][s * 8 + q] = (float)v8[q] * m;
            }
        }
    }
    // wave-synchronous: same wave wrote, same wave reads — compiler inserts lgkmcnt
    int e = lane & 31, d0 = (lane >> 5) * 16;
    float kv[16], ksl[16];
    #pragma unroll
    for (int j = 0; j < 16; j++) { kv[j] = 0.f; ksl[j] = 0.f; }
    for (int t = 0; t < CHUNK; t++) {
        float ve = vs[t][e];
        f32x4 kr[4];
        #pragma unroll
        for (int s = 0; s < 4; s++) kr[s] = *(const f32x4*)&ks[t][d0 + s * 4];
        #pragma unroll
        for (int j = 0; j < 16; j++) {
            float kval = kr[j >> 2][j & 3];
            kv[j] = fmaf(kval, ve, kv[j]);
            ksl[j] += kval;
        }
    }
    size_t base = (size_t)ci * 1024;
    #pragma unroll
    for (int j = 0; j < 16; j++)
        kvsum[base + (size_t)(d0 + j) * 32 + e] = kv[j];
    if (e == 0) {
        #pragma unroll
        for (int j = 0; j < 16; j++)
            kssum[ci * 32 + d0 + j] = ksl[j];
    }
}

// Phase B: exclusive prefix over chunks, per (b,h).
__global__ __launch_bounds__(256) void attn_prefix(
    const float* __restrict__ kvsum, const float* __restrict__ kssum,
    float* __restrict__ kvpref, float* __restrict__ kspref)
{
    int bh = blockIdx.x;
    int tid = threadIdx.x;
    float run[4] = {0.f, 0.f, 0.f, 0.f};
    for (int c = 0; c < NCH; c++) {
        size_t base = (size_t)(bh * NCH + c) * 1024 + tid * 4;
        #pragma unroll
        for (int q = 0; q < 4; q++) {
            kvpref[base + q] = run[q];
            run[q] += kvsum[base + q];
        }
    }
    if (tid < 32) {
        float r = 0.f;
        for (int c = 0; c < NCH; c++) {
            kspref[(bh * NCH + c) * 32 + tid] = r;
            r += kssum[(bh * NCH + c) * 32 + tid];
        }
    }
}

// Phase C: in-chunk scan, LDS-resident.
__global__ __launch_bounds__(64) void attn_scan(
    const bf16* __restrict__ proj, const float* __restrict__ mask,
    const float* __restrict__ kvpref, const float* __restrict__ kspref,
    bf16* __restrict__ attn_out)
{
    int blk = blockIdx.x;
    int c  = blk & (NCH - 1);
    int bh = blk >> 5;
    int b  = bh >> 4, hh = bh & (HH - 1);
    int lane = threadIdx.x;
    __shared__ float qs[CHUNK][32], ks[CHUNK][32], vs[CHUNK][32];
    __shared__ float ms[CHUNK];
    int row0 = b * TT + c * CHUNK;
    {
        int row = row0 + lane;
        float m = mask[row];
        ms[lane] = m;
        const bf16* qp = proj + (size_t)row * NPROJ + DD + hh * 32;
        const bf16* kp = qp + INNERD;
        const bf16* vp = kp + INNERD;
        #pragma unroll
        for (int s = 0; s < 4; s++) {
            bf16x8 q8 = *(const bf16x8*)(qp + s * 8);
            bf16x8 k8 = *(const bf16x8*)(kp + s * 8);
            bf16x8 v8 = *(const bf16x8*)(vp + s * 8);
            #pragma unroll
            for (int q = 0; q < 8; q++) {
                qs[lane][s * 8 + q] = phi_f((float)q8[q]) * m;
                ks[lane][s * 8 + q] = phi_f((float)k8[q]) * m;
                vs[lane][s * 8 + q] = (float)v8[q] * m;
            }
        }
    }
    int e = lane & 31, d0 = (lane >> 5) * 16;
    float kv[16], ksl[16];
    size_t base = (size_t)blk * 1024;
    #pragma unroll
    for (int j = 0; j < 16; j++) kv[j] = kvpref[base + (size_t)(d0 + j) * 32 + e];
    #pragma unroll
    for (int j = 0; j < 16; j++) ksl[j] = kspref[blk * 32 + d0 + j];
    __syncthreads();
    for (int t = 0; t < CHUNK; t++) {
        float ve = vs[t][e];
        f32x4 kr[4], qr[4];
        #pragma unroll
        for (int s = 0; s < 4; s++) kr[s] = *(const f32x4*)&ks[t][d0 + s * 4];
        #pragma unroll
        for (int s = 0; s < 4; s++) qr[s] = *(const f32x4*)&qs[t][d0 + s * 4];
        float num0 = 0.f, num1 = 0.f, den0 = 0.f, den1 = 0.f;
        #pragma unroll
        for (int j = 0; j < 16; j++) {
            float kval = kr[j >> 2][j & 3], qval = qr[j >> 2][j & 3];
            kv[j]  = fmaf(kval, ve, kv[j]);   // inclusive cumsum
            ksl[j] += kval;
            if (j & 1) { num1 = fmaf(qval, kv[j], num1); den1 = fmaf(qval, ksl[j], den1); }
            else       { num0 = fmaf(qval, kv[j], num0); den0 = fmaf(qval, ksl[j], den0); }
        }
        float num = num0 + num1, den = den0 + den1;
        num += __shfl_xor(num, 32, 64);
        den += __shfl_xor(den, 32, 64);
        if (lane < 32)
            attn_out[(size_t)(row0 + t) * INNERD + hh * 32 + e] =
                (bf16)(num / (den + 1e-6f) * ms[t]);
    }
}

// ---------------------------------------------------------------- launch
extern "C" void kernel_launch(void* const* d_in, const int* in_sizes, int n_in,
                              void* d_out, int out_size, void* d_ws, size_t ws_size,
                              hipStream_t stream)
{
    const float* inputs = (const float*)d_in[0];
    const float* mask   = (const float*)d_in[1];
    const float* ln1_g  = (const float*)d_in[2];
    const float* ln1_b  = (const float*)d_in[3];
    const float* W_in   = (const float*)d_in[4];
    const float* b_in   = (const float*)d_in[5];
    const float* W_c    = (const float*)d_in[6];
    const float* b_c    = (const float*)d_in[7];
    const float* w_t    = (const float*)d_in[8];
    const float* b_t    = (const float*)d_in[9];
    const float* w_p    = (const float*)d_in[10];
    const float* b_p    = (const float*)d_in[11];
    const float* W_mix  = (const float*)d_in[12];
    const float* b_mix  = (const float*)d_in[13];
    const float* ln2_g  = (const float*)d_in[14];
    const float* ln2_b  = (const float*)d_in[15];
    const float* W1     = (const float*)d_in[16];
    const float* b1     = (const float*)d_in[17];
    const float* W2     = (const float*)d_in[18];
    const float* b2     = (const float*)d_in[19];
    float* out = (float*)d_out;

    // workspace layout (bytes). ffn1 aliases [normed|proj|attnb] (dead by W1).
    // attn kv scratch aliases out1 (dead until epi_mix_ln2).
    // Split-K bf16 partials (non-atomic, fully overwritten by their GEMM):
    //   W_c : d_out, out1-region
    //   W_mix: d_out (2 partials), hbuf-region
    //   W2  : cat-region (3 partials), hbuf-region
    char* p = (char*)d_ws;
    bf16* normed = (bf16*)p;  p += (size_t)MROWS * DD * 2;
    bf16* proj   = (bf16*)p;  p += (size_t)MROWS * NPROJ * 2;
    bf16* attnb  = (bf16*)p;  p += (size_t)MROWS * INNERD * 2;
    bf16* cat    = (bf16*)p;  p += (size_t)MROWS * CATD * 2;
    float* out1  = (float*)p; p += (size_t)MROWS * DD * 4;
    bf16* hbuf   = (bf16*)p;  p += (size_t)MROWS * DD * 2;
    bf16* wt_in  = (bf16*)p;  p += (size_t)NPROJ * DD * 2;
    bf16* wt_c   = (bf16*)p;  p += (size_t)DD * INNERD * 2;
    bf16* wt_mix = (bf16*)p;  p += (size_t)DD * CATD * 2;
    bf16* wt1    = (bf16*)p;  p += (size_t)FFD * DD * 2;
    bf16* wt2    = (bf16*)p;  p += (size_t)DD * FFD * 2;
    bf16* ffn1   = (bf16*)d_ws;                  // alias [normed|proj|attnb]
    float* kvsum = out1;                         // alias out1 region (attn)
    float* kvpref= kvsum  + (size_t)BH * NCH * 1024;
    float* kssum = kvpref + (size_t)BH * NCH * 1024;
    float* kspref= kssum  + (size_t)BH * NCH * 32;
    // split-K bf16 partials
    bf16*  c_p0  = (bf16*)d_out;
    bf16*  c_p1  = (bf16*)out1;
    bf16*  m_p0  = (bf16*)d_out;
    bf16*  m_p1  = (bf16*)d_out + (size_t)MROWS * DD;
    bf16*  m_p2  = hbuf;
    bf16*  w2_p0 = cat;
    bf16*  w2_p1 = cat + (size_t)MROWS * DD;
    bf16*  w2_p2 = cat + (size_t)MROWS * DD * 2;
    bf16*  w2_p3 = hbuf;

    // 1. fused prep: LN1 + all 5 weight transposes (one dispatch)
    prep_fused<<<MROWS + 14336, 256, 0, stream>>>(
        inputs, ln1_g, ln1_b, normed,
        W_in, wt_in, W_c, wt_c, W_mix, wt_mix, W1, wt1, W2, wt2);
    // 2. proj = normed @ W_in + b_in (bf16 out)   grid (M,N)
    gemm256<0><<<dim3(MROWS/256, NPROJ/256), 512, 0, stream>>>(
        normed, DD, wt_in, DD, b_in, proj, NPROJ, DD, Part4{});
    // 3. fused dwconv + attn phase A (one dispatch)
    mid_fused<<<1024 + 512, 256, 0, stream>>>(
        normed, w_t, b_t, w_p, b_p, cat, proj, mask, kvsum, kssum);
    attn_prefix<<<BH, 256, 0, stream>>>(kvsum, kssum, kvpref, kspref);
    attn_scan  <<<BH * NCH, 64, 0, stream>>>(proj, mask, kvpref, kspref, attnb);
    // 5. W_c split-2 bf16 partials, then cat[:,0:D] = bf16(P0+P1+b_c)
    gemm256<4><<<dim3(MROWS/256, DD/256, 2), 512, 0, stream>>>(
        attnb, INNERD, wt_c, INNERD, nullptr, nullptr, DD, INNERD / 2,
        Part4{c_p0, c_p1, nullptr, nullptr});
    epi_wc<<<MROWS * DD / 4 / 256, 256, 0, stream>>>(c_p0, c_p1, b_c, cat);
    // 6. W_mix split-3 bf16 partials
    gemm256<4><<<dim3(MROWS/256, DD/256, 3), 512, 0, stream>>>(
        cat, CATD, wt_mix, CATD, nullptr, nullptr, DD, CATD / 3,
        Part4{m_p0, m_p1, m_p2, nullptr});
    // 7. out1 = (inputs + sigmoid(gate)*(sum P + b_mix))*mask ; hbuf = LN2(out1)
    epi_mix_ln2<<<MROWS, 256, 0, stream>>>(m_p0, m_p1, m_p2, b_mix, proj, inputs,
                                           mask, ln2_g, ln2_b, out1, hbuf);
    // 8. ffn1 = gelu(hbuf @ W1 + b1) (bf16 out; aliases dead normed/proj/attnb)
    gemm256<1><<<dim3(MROWS/256, FFD/256), 512, 0, stream>>>(
        hbuf, DD, wt1, DD, b1, ffn1, FFD, DD, Part4{});
    // 9. W2 split-4 bf16 partials
    gemm256<4><<<dim3(MROWS/256, DD/256, 4), 512, 0, stream>>>(
        ffn1, FFD, wt2, FFD, nullptr, nullptr, DD, FFD / 4,
        Part4{w2_p0, w2_p1, w2_p2, w2_p3});
    // 10. out = (out1 + sum P + b2) * mask
    epi_w2<<<MROWS * DD / 4 / 256, 256, 0, stream>>>(out, out1, w2_p0, w2_p1,
                                                     w2_p2, w2_p3, b2, mask);
}

// Round 4
// 410.756 us; speedup vs baseline: 1.0571x; 1.0097x over previous
//
#include <hip/hip_runtime.h>
#include <math.h>

#define BB 2
#define TT 2048
#define DD 1024
#define HH 16
#define INNERD 512
#define FFD 4096
#define NPROJ 2560     // D + 3*INNER
#define CATD2 2560     // 512 (attn) + 1024 (temporal) + 1024 (positional)
#define MROWS (BB*TT)  // 4096
#define CHUNK 64
#define NCH (TT/CHUNK) // 32
#define BH 32          // B*H

typedef __bf16 bf16;
typedef __attribute__((ext_vector_type(8))) __bf16 bf16x8;
typedef __attribute__((ext_vector_type(4))) __bf16 bf16x4;
typedef __attribute__((ext_vector_type(4))) float f32x4;

struct Part4 { void* p0; void* p1; void* p2; void* p3; };

// ---------------------------------------------------------------- fused prep:
// blocks [0,4096): LN1 row kernel
// blocks [4096,17920): 32x32 transpose tiles for W_in, W_mix(split-target), W1, W2
// block  17920: bmix2 = b_mix (init for prep2's atomic fold)
__global__ __launch_bounds__(256) void prep_fused(
    const float* __restrict__ inputs, const float* __restrict__ ln1_g,
    const float* __restrict__ ln1_b, bf16* __restrict__ normed,
    const float* __restrict__ W_in,  bf16* __restrict__ wt_in,
    const float* __restrict__ W_mix, bf16* __restrict__ wt_m0,
    bf16* __restrict__ wt_comb,
    const float* __restrict__ W1,    bf16* __restrict__ wt1,
    const float* __restrict__ W2,    bf16* __restrict__ wt2,
    const float* __restrict__ b_mix, float* __restrict__ bmix2)
{
    int blk = blockIdx.x, tid = threadIdx.x;
    if (blk < MROWS) {
        // ---- LN1 ----
        int row = blk;
        f32x4 xv = ((const f32x4*)(inputs + (size_t)row * DD))[tid];
        float s = xv[0] + xv[1] + xv[2] + xv[3];
        float s2 = xv[0]*xv[0] + xv[1]*xv[1] + xv[2]*xv[2] + xv[3]*xv[3];
        #pragma unroll
        for (int off = 32; off > 0; off >>= 1) {
            s  += __shfl_xor(s,  off, 64);
            s2 += __shfl_xor(s2, off, 64);
        }
        __shared__ float rs[4], rs2[4];
        int wid = tid >> 6;
        if ((tid & 63) == 0) { rs[wid] = s; rs2[wid] = s2; }
        __syncthreads();
        s  = rs[0] + rs[1] + rs[2] + rs[3];
        s2 = rs2[0] + rs2[1] + rs2[2] + rs2[3];
        float mean = s * (1.0f / DD);
        float var  = s2 * (1.0f / DD) - mean * mean;
        float rstd = rsqrtf(var + 1e-5f);
        f32x4 gv = ((const f32x4*)ln1_g)[tid];
        f32x4 bv = ((const f32x4*)ln1_b)[tid];
        bf16x4 o;
        #pragma unroll
        for (int q = 0; q < 4; q++)
            o[q] = (bf16)((xv[q] - mean) * rstd * gv[q] + bv[q]);
        ((bf16x4*)(normed + (size_t)row * DD))[tid] = o;
        return;
    }
    int tb = blk - MROWS;
    if (tb == 13824) {           // bmix2 init
        ((f32x4*)bmix2)[tid] = ((const f32x4*)b_mix)[tid];
        return;
    }
    // ---- transpose fp32(K,N) -> bf16(N,K), 32x32 tiles ----
    const float* W; bf16* Wt = nullptr; int Kd, Nd; bool is_mix = false;
    if      (tb < 2560)  {             W = W_in;  Wt = wt_in;  Kd = 1024; Nd = 2560; }
    else if (tb < 5632)  { tb -= 2560; W = W_mix;              Kd = 3072; Nd = 1024; is_mix = true; }
    else if (tb < 9728)  { tb -= 5632; W = W1;    Wt = wt1;    Kd = 1024; Nd = 4096; }
    else                 { tb -= 9728; W = W2;    Wt = wt2;    Kd = 4096; Nd = 1024; }
    int ntx = Nd >> 5;
    int nb = (tb % ntx) * 32, kb = (tb / ntx) * 32;
    int ldW = Kd, kw = kb;
    if (is_mix) {
        if (kb < 1024) { Wt = wt_m0;   ldW = 1024;  kw = kb; }
        else           { Wt = wt_comb; ldW = CATD2; kw = kb - 512; }  // cols 512..2559
    }
    __shared__ float t[32][33];
    int tx = tid & 31, ty = tid >> 5;   // 32 x 8
    #pragma unroll
    for (int r = 0; r < 32; r += 8)
        t[ty + r][tx] = W[(size_t)(kb + ty + r) * Nd + nb + tx];
    __syncthreads();
    #pragma unroll
    for (int r = 0; r < 32; r += 8)
        Wt[(size_t)(nb + ty + r) * ldW + kw + tx] = (bf16)t[tx][ty + r];
}

// ---------------------------------------------------------------- prep2:
// blocks [0,512): cast W_c fp32 -> bf16 (row-major 512x1024, GEMM B-operand)
// blocks [512,576): bmix2 += b_c @ W_mix[0:1024]  (16 j-slices x 4 n-blocks)
__global__ __launch_bounds__(256) void prep2(
    const float* __restrict__ W_c, bf16* __restrict__ wc_b,
    const float* __restrict__ b_c, const float* __restrict__ W_mix,
    float* __restrict__ bmix2)
{
    int blk = blockIdx.x, tid = threadIdx.x;
    if (blk < 512) {
        int id = blk * 256 + tid;            // over 131072 f32x4
        f32x4 v = ((const f32x4*)W_c)[id];
        bf16x4 o;
        #pragma unroll
        for (int q = 0; q < 4; q++) o[q] = (bf16)v[q];
        ((bf16x4*)wc_b)[id] = o;
        return;
    }
    int s = blk - 512;                       // 0..63
    int n  = (s & 3) * 256 + tid;
    int j0 = (s >> 2) * 64;
    float acc = 0.f;
    #pragma unroll 8
    for (int j = 0; j < 64; j++)
        acc = fmaf(b_c[j0 + j], W_mix[(size_t)(j0 + j) * DD + n], acc);
    atomicAdd(&bmix2[n], acc);
}

// ---------------------------------------------------------------- MFMA GEMM, BK=64, 4 blocks/CU
// (verified round-0 structure: 128x128 tile, 2-barrier K-loop, global_load_lds w16)
// EPI 0: +bias -> bf16 Cb      EPI 1: fast-gelu(+bias) -> bf16 Cb
// EPI 4: bf16 partial -> part.p[z] (ldc=DD)   EPI 5: plain bf16 -> Cb (no bias)
template<int EPI>
__global__ __launch_bounds__(256, 4) void gemm_mfma(
    const bf16* __restrict__ A,  int lda,
    const bf16* __restrict__ Bt, int ldb,
    const float* __restrict__ bias,
    bf16* __restrict__ Cb, int ldc,
    int K, Part4 part)
{
    __shared__ bf16 As[128 * 64];   // chunk-contiguous: 16 chunks of 16rows x 32k
    __shared__ bf16 Bs[128 * 64];
    const int tid  = threadIdx.x;
    const int wave = tid >> 6, lane = tid & 63;
    const int m0 = blockIdx.x * 128, n0 = blockIdx.y * 128;
    const int koff = blockIdx.z * K;
    A  += koff;
    Bt += koff;
    const int wr = wave >> 1, wc = wave & 1;
    const int lrow = lane >> 2;          // staging row within 16-row chunk
    const int lcol = (lane & 3) * 8;     // staging k offset within 32-k half
    const int fm = lane & 15;            // fragment m/n within 16-tile
    const int fk = (lane >> 4) * 8;      // fragment k offset

    f32x4 acc[4][4];
    #pragma unroll
    for (int i = 0; i < 4; i++)
        #pragma unroll
        for (int j = 0; j < 4; j++)
            acc[i][j] = (f32x4){0.f, 0.f, 0.f, 0.f};

    for (int k0 = 0; k0 < K; k0 += 64) {
        #pragma unroll
        for (int r = 0; r < 4; r++) {
            int c  = r * 4 + wave;            // chunk 0..15
            int rc = c >> 1, kh = c & 1;      // row-chunk, k-half
            const bf16* ga = A  + (size_t)(m0 + rc * 16 + lrow) * lda + k0 + kh * 32 + lcol;
            const bf16* gb = Bt + (size_t)(n0 + rc * 16 + lrow) * ldb + k0 + kh * 32 + lcol;
            __builtin_amdgcn_global_load_lds(
                (const __attribute__((address_space(1))) void*)ga,
                (__attribute__((address_space(3))) void*)(As + c * 512), 16, 0, 0);
            __builtin_amdgcn_global_load_lds(
                (const __attribute__((address_space(1))) void*)gb,
                (__attribute__((address_space(3))) void*)(Bs + c * 512), 16, 0, 0);
        }
        __syncthreads();
        #pragma unroll
        for (int ks = 0; ks < 2; ks++) {
            bf16x8 af[4], bfv[4];
            #pragma unroll
            for (int i = 0; i < 4; i++)
                af[i] = *(const bf16x8*)(As + (wr * 4 + i) * 1024 + ks * 512 + fm * 32 + fk);
            #pragma unroll
            for (int j = 0; j < 4; j++)
                bfv[j] = *(const bf16x8*)(Bs + (wc * 4 + j) * 1024 + ks * 512 + fm * 32 + fk);
            #pragma unroll
            for (int i = 0; i < 4; i++)
                #pragma unroll
                for (int j = 0; j < 4; j++)
                    acc[i][j] = __builtin_amdgcn_mfma_f32_16x16x32_bf16(
                        af[i], bfv[j], acc[i][j], 0, 0, 0);
        }
        __syncthreads();
    }

    void* psel = nullptr;
    if constexpr (EPI == 4) {
        int z = blockIdx.z;
        psel = (z == 0) ? part.p0 : (z == 1) ? part.p1 : (z == 2) ? part.p2 : part.p3;
    }

    #pragma unroll
    for (int i = 0; i < 4; i++) {
        int mbase = m0 + wr * 64 + i * 16 + (lane >> 4) * 4;
        #pragma unroll
        for (int j = 0; j < 4; j++) {
            int col = n0 + wc * 64 + j * 16 + (lane & 15);
            float bv = 0.f;
            if constexpr (EPI == 0 || EPI == 1) bv = bias[col];
            #pragma unroll
            for (int r = 0; r < 4; r++) {
                int row = mbase + r;
                float v = acc[i][j][r] + bv;
                if constexpr (EPI == 0) {
                    Cb[(size_t)row * ldc + col] = (bf16)v;
                } else if constexpr (EPI == 1) {
                    // fast gelu: x * sigmoid(1.5957691x + 0.07135502x^3)
                    float z2 = v * (1.5957691f + 0.07135502f * v * v);
                    v = v / (1.0f + __expf(-z2));
                    Cb[(size_t)row * ldc + col] = (bf16)v;
                } else if constexpr (EPI == 5) {
                    Cb[(size_t)row * ldc + col] = (bf16)v;
                } else {
                    ((bf16*)psel)[(size_t)row * DD + col] = (bf16)v;
                }
            }
        }
    }
}

// ---------------------------------------------------------------- fused epilogue: mix (2 bf16 partials) gate + residual + mask, then LN2
__global__ __launch_bounds__(256) void epi_mix_ln2(
    const bf16* __restrict__ P0, const bf16* __restrict__ P1,
    const float* __restrict__ bias,
    const bf16* __restrict__ proj, const float* __restrict__ res,
    const float* __restrict__ mask,
    const float* __restrict__ g2, const float* __restrict__ b2v,
    float* __restrict__ out1, bf16* __restrict__ hbuf)
{
    int row = blockIdx.x, tid = threadIdx.x;
    float m = mask[row];
    size_t off = (size_t)row * DD + tid * 4;
    bf16x4 s0 = *(const bf16x4*)(P0 + off);
    bf16x4 s1 = *(const bf16x4*)(P1 + off);
    f32x4 bv = ((const f32x4*)bias)[tid];
    bf16x4 g4 = *(const bf16x4*)(proj + (size_t)row * NPROJ + tid * 4);
    f32x4 rv = ((const f32x4*)(res + (size_t)row * DD))[tid];
    f32x4 v;
    #pragma unroll
    for (int q = 0; q < 4; q++) {
        float sg = 1.0f / (1.0f + __expf(-(float)g4[q]));
        float sv = (float)s0[q] + (float)s1[q] + bv[q];
        v[q] = (rv[q] + sg * sv) * m;
    }
    ((f32x4*)(out1 + (size_t)row * DD))[tid] = v;
    // LN2
    float s = v[0] + v[1] + v[2] + v[3];
    float s2 = v[0]*v[0] + v[1]*v[1] + v[2]*v[2] + v[3]*v[3];
    #pragma unroll
    for (int off2 = 32; off2 > 0; off2 >>= 1) {
        s  += __shfl_xor(s,  off2, 64);
        s2 += __shfl_xor(s2, off2, 64);
    }
    __shared__ float rs[4], rs2[4];
    int wid = tid >> 6;
    if ((tid & 63) == 0) { rs[wid] = s; rs2[wid] = s2; }
    __syncthreads();
    s  = rs[0] + rs[1] + rs[2] + rs[3];
    s2 = rs2[0] + rs2[1] + rs2[2] + rs2[3];
    float mean = s * (1.0f / DD);
    float var  = s2 * (1.0f / DD) - mean * mean;
    float rstd = rsqrtf(var + 1e-5f);
    f32x4 gg = ((const f32x4*)g2)[tid];
    f32x4 bb = ((const f32x4*)b2v)[tid];
    bf16x4 h;
    #pragma unroll
    for (int q = 0; q < 4; q++)
        h[q] = (bf16)((v[q] - mean) * rstd * gg[q] + bb[q]);
    ((bf16x4*)(hbuf + (size_t)row * DD))[tid] = h;
}

// ---------------------------------------------------------------- final epilogue: out = (out1 + sum 4 bf16 partials + b2) * mask
__global__ __launch_bounds__(256) void epi_w2(
    float* __restrict__ d_out, const float* __restrict__ out1,
    const bf16* __restrict__ P0, const bf16* __restrict__ P1,
    const bf16* __restrict__ P2, const bf16* __restrict__ P3,
    const float* __restrict__ bias, const float* __restrict__ mask)
{
    int id = blockIdx.x * 256 + threadIdx.x;    // over MROWS*DD/4
    int row = id >> 8;                          // 256 f32x4 per row
    float m = mask[row];
    bf16x4 a0 = ((const bf16x4*)P0)[id];
    bf16x4 a1 = ((const bf16x4*)P1)[id];
    bf16x4 a2 = ((const bf16x4*)P2)[id];
    bf16x4 a3 = ((const bf16x4*)P3)[id];
    f32x4 r = ((const f32x4*)out1)[id];
    f32x4 b = ((const f32x4*)bias)[id & 255];
    f32x4 o;
    #pragma unroll
    for (int q = 0; q < 4; q++) {
        float sv = (float)a0[q] + (float)a1[q] + (float)a2[q] + (float)a3[q];
        o[q] = (r[q] + sv + b[q]) * m;
    }
    ((f32x4*)d_out)[id] = o;
}

// ---------------------------------------------------------------- attention helpers
__device__ __forceinline__ float phi_f(float x) {
    return x > 0.f ? x + 1.f : __expf(x);   // elu(x)+1
}

// ---------------------------------------------------------------- mid fused:
// blocks [0,1024): dwconv (both kernels, 2 rows/thread, vectorized) -> cat cols [512,2560)
// blocks [1024,1536): attn phase A local sums — waves 0,1 each own one chunk
__global__ __launch_bounds__(256) void mid_fused(
    const bf16* __restrict__ x,
    const float* __restrict__ w_t, const float* __restrict__ b_t,
    const float* __restrict__ w_p, const float* __restrict__ b_p,
    bf16* __restrict__ cat,
    const bf16* __restrict__ proj, const float* __restrict__ mask,
    float* __restrict__ kvsum, float* __restrict__ kssum)
{
    __shared__ float s_ks[2][CHUNK][32], s_vs[2][CHUNK][32];   // 32 KB
    int blk = blockIdx.x, tid = threadIdx.x;
    if (blk < 1024) {
        // ---- dwconv ----
        int id = blk * 256 + tid;                // over (MROWS/2)*128
        int cg = id & 127, rp = id >> 7;
        int c0 = cg * 8;
        int row0 = rp * 2;
        int t0 = row0 & (TT - 1);
        bf16x8 xw[16];
        #pragma unroll
        for (int j = 0; j < 16; j++) {
            int t = t0 - 14 + j;
            if (t >= 0)
                xw[j] = *(const bf16x8*)(x + (size_t)(row0 - 14 + j) * DD + c0);
            else
                #pragma unroll
                for (int q = 0; q < 8; q++) xw[j][q] = (bf16)0.f;
        }
        float y15[2][8], y3[2][8];
        #pragma unroll
        for (int q = 0; q < 8; q++) {
            float bp = b_p[c0 + q], bt = b_t[c0 + q];
            y15[0][q] = bp; y15[1][q] = bp;
            y3[0][q] = bt;  y3[1][q] = bt;
        }
        #pragma unroll
        for (int i = 0; i < 15; i++) {
            float wp[8];
            #pragma unroll
            for (int q = 0; q < 8; q++) wp[q] = w_p[(c0 + q) * 15 + i];
            #pragma unroll
            for (int rr = 0; rr < 2; rr++)
                #pragma unroll
                for (int q = 0; q < 8; q++)
                    y15[rr][q] = fmaf(wp[q], (float)xw[rr + i][q], y15[rr][q]);
        }
        #pragma unroll
        for (int i = 0; i < 3; i++) {
            float wt[8];
            #pragma unroll
            for (int q = 0; q < 8; q++) wt[q] = w_t[(c0 + q) * 3 + i];
            #pragma unroll
            for (int rr = 0; rr < 2; rr++)
                #pragma unroll
                for (int q = 0; q < 8; q++)
                    y3[rr][q] = fmaf(wt[q], (float)xw[rr + 12 + i][q], y3[rr][q]);
        }
        #pragma unroll
        for (int rr = 0; rr < 2; rr++) {
            bf16x8 o3, o15;
            #pragma unroll
            for (int q = 0; q < 8; q++) { o3[q] = (bf16)y3[rr][q]; o15[q] = (bf16)y15[rr][q]; }
            *(bf16x8*)(cat + (size_t)(row0 + rr) * CATD2 + 512 + c0)  = o3;
            *(bf16x8*)(cat + (size_t)(row0 + rr) * CATD2 + 1536 + c0) = o15;
        }
        return;
    }
    // ---- attn phase A ----
    int w = tid >> 6;
    if (w >= 2) return;
    int lane = tid & 63;
    int ci = (blk - 1024) * 2 + w;     // chunk id 0..1023 == bh*NCH + c
    int c  = ci & (NCH - 1);
    int bh = ci >> 5;
    int b  = bh >> 4, hh = bh & (HH - 1);
    float (*ks)[32] = s_ks[w];
    float (*vs)[32] = s_vs[w];
    int row0 = b * TT + c * CHUNK;
    {
        int row = row0 + lane;
        float m = mask[row];
        const bf16* kp = proj + (size_t)row * NPROJ + DD + INNERD + hh * 32;
        const bf16* vp = kp + INNERD;
        #pragma unroll
        for (int s = 0; s < 4; s++) {
            bf16x8 k8 = *(const bf16x8*)(kp + s * 8);
            bf16x8 v8 = *(const bf16x8*)(vp + s * 8);
            #pragma unroll
            for (int q = 0; q < 8; q++) {
                ks[lane][s * 8 + q] = phi_f((float)k8[q]) * m;
                vs[lane][s * 8 + q] = (float)v8[q] * m;
            }
        }
    }
    // wave-synchronous: same wave wrote, same wave reads — compiler inserts lgkmcnt
    int e = lane & 31, d0 = (lane >> 5) * 16;
    float kv[16], ksl[16];
    #pragma unroll
    for (int j = 0; j < 16; j++) { kv[j] = 0.f; ksl[j] = 0.f; }
    for (int t = 0; t < CHUNK; t++) {
        float ve = vs[t][e];
        f32x4 kr[4];
        #pragma unroll
        for (int s = 0; s < 4; s++) kr[s] = *(const f32x4*)&ks[t][d0 + s * 4];
        #pragma unroll
        for (int j = 0; j < 16; j++) {
            float kval = kr[j >> 2][j & 3];
            kv[j] = fmaf(kval, ve, kv[j]);
            ksl[j] += kval;
        }
    }
    size_t base = (size_t)ci * 1024;
    #pragma unroll
    for (int j = 0; j < 16; j++)
        kvsum[base + (size_t)(d0 + j) * 32 + e] = kv[j];
    if (e == 0) {
        #pragma unroll
        for (int j = 0; j < 16; j++)
            kssum[ci * 32 + d0 + j] = ksl[j];
    }
}

// Phase B: exclusive prefix over chunks — parallel (one scan per thread).
// blocks [0,128): kv scans (32768 of them); blocks [128,132): ks scans (1024)
__global__ __launch_bounds__(256) void attn_prefix(
    const float* __restrict__ kvsum, const float* __restrict__ kssum,
    float* __restrict__ kvpref, float* __restrict__ kspref)
{
    int blk = blockIdx.x, tid = threadIdx.x;
    if (blk < 128) {
        int bh = blk >> 2;
        int de = (blk & 3) * 256 + tid;
        float run = 0.f;
        for (int c = 0; c < NCH; c++) {
            size_t a = (size_t)(bh * NCH + c) * 1024 + de;
            kvpref[a] = run;
            run += kvsum[a];
        }
        return;
    }
    int id = (blk - 128) * 256 + tid;   // 0..1023 = bh*32 + d
    int bh = id >> 5, d = id & 31;
    float r = 0.f;
    for (int c = 0; c < NCH; c++) {
        int a = (bh * NCH + c) * 32 + d;
        kspref[a] = r;
        r += kssum[a];
    }
}

// Phase C: in-chunk scan, LDS-resident. Writes attn output into cat[:,0:512).
__global__ __launch_bounds__(64) void attn_scan(
    const bf16* __restrict__ proj, const float* __restrict__ mask,
    const float* __restrict__ kvpref, const float* __restrict__ kspref,
    bf16* __restrict__ cat)
{
    int blk = blockIdx.x;
    int c  = blk & (NCH - 1);
    int bh = blk >> 5;
    int b  = bh >> 4, hh = bh & (HH - 1);
    int lane = threadIdx.x;
    __shared__ float qs[CHUNK][32], ks[CHUNK][32], vs[CHUNK][32];
    __shared__ float ms[CHUNK];
    int row0 = b * TT + c * CHUNK;
    {
        int row = row0 + lane;
        float m = mask[row];
        ms[lane] = m;
        const bf16* qp = proj + (size_t)row * NPROJ + DD + hh * 32;
        const bf16* kp = qp + INNERD;
        const bf16* vp = kp + INNERD;
        #pragma unroll
        for (int s = 0; s < 4; s++) {
            bf16x8 q8 = *(const bf16x8*)(qp + s * 8);
            bf16x8 k8 = *(const bf16x8*)(kp + s * 8);
            bf16x8 v8 = *(const bf16x8*)(vp + s * 8);
            #pragma unroll
            for (int q = 0; q < 8; q++) {
                qs[lane][s * 8 + q] = phi_f((float)q8[q]) * m;
                ks[lane][s * 8 + q] = phi_f((float)k8[q]) * m;
                vs[lane][s * 8 + q] = (float)v8[q] * m;
            }
        }
    }
    int e = lane & 31, d0 = (lane >> 5) * 16;
    float kv[16], ksl[16];
    size_t base = (size_t)blk * 1024;
    #pragma unroll
    for (int j = 0; j < 16; j++) kv[j] = kvpref[base + (size_t)(d0 + j) * 32 + e];
    #pragma unroll
    for (int j = 0; j < 16; j++) ksl[j] = kspref[blk * 32 + d0 + j];
    __syncthreads();
    for (int t = 0; t < CHUNK; t++) {
        float ve = vs[t][e];
        f32x4 kr[4], qr[4];
        #pragma unroll
        for (int s = 0; s < 4; s++) kr[s] = *(const f32x4*)&ks[t][d0 + s * 4];
        #pragma unroll
        for (int s = 0; s < 4; s++) qr[s] = *(const f32x4*)&qs[t][d0 + s * 4];
        float num0 = 0.f, num1 = 0.f, den0 = 0.f, den1 = 0.f;
        #pragma unroll
        for (int j = 0; j < 16; j++) {
            float kval = kr[j >> 2][j & 3], qval = qr[j >> 2][j & 3];
            kv[j]  = fmaf(kval, ve, kv[j]);   // inclusive cumsum
            ksl[j] += kval;
            if (j & 1) { num1 = fmaf(qval, kv[j], num1); den1 = fmaf(qval, ksl[j], den1); }
            else       { num0 = fmaf(qval, kv[j], num0); den0 = fmaf(qval, ksl[j], den0); }
        }
        float num = num0 + num1, den = den0 + den1;
        num += __shfl_xor(num, 32, 64);
        den += __shfl_xor(den, 32, 64);
        if (lane < 32)
            cat[(size_t)(row0 + t) * CATD2 + hh * 32 + e] =
                (bf16)(num / (den + 1e-6f) * ms[t]);
    }
}

// ---------------------------------------------------------------- launch
extern "C" void kernel_launch(void* const* d_in, const int* in_sizes, int n_in,
                              void* d_out, int out_size, void* d_ws, size_t ws_size,
                              hipStream_t stream)
{
    const float* inputs = (const float*)d_in[0];
    const float* mask   = (const float*)d_in[1];
    const float* ln1_g  = (const float*)d_in[2];
    const float* ln1_b  = (const float*)d_in[3];
    const float* W_in   = (const float*)d_in[4];
    const float* b_in   = (const float*)d_in[5];
    const float* W_c    = (const float*)d_in[6];
    const float* b_c    = (const float*)d_in[7];
    const float* w_t    = (const float*)d_in[8];
    const float* b_t    = (const float*)d_in[9];
    const float* w_p    = (const float*)d_in[10];
    const float* b_p    = (const float*)d_in[11];
    const float* W_mix  = (const float*)d_in[12];
    const float* b_mix  = (const float*)d_in[13];
    const float* ln2_g  = (const float*)d_in[14];
    const float* ln2_b  = (const float*)d_in[15];
    const float* W1     = (const float*)d_in[16];
    const float* b1     = (const float*)d_in[17];
    const float* W2     = (const float*)d_in[18];
    const float* b2     = (const float*)d_in[19];
    float* out = (float*)d_out;

    // workspace layout (MiB offsets):
    //   normed [0,8)  proj [8,28)  cat [28,48)  out1 [48,64)  hbuf [64,72)
    //   wt_in [72,77) wt_m0 [77,79) wt_comb [79,84) wt1 [84,92) wt2 [92,100)
    //   wc_b [100,101) bmix2
    // Aliases:
    //   ffn1 (32 MiB) = [0,32) = normed|proj|cat[0:4MiB]  (all dead by W1 GEMM)
    //   attn kv scratch aliases out1 (dead until epi_mix_ln2)
    //   mix partials: d_out (2 x 8 MiB bf16)
    //   W2 partials: MUST be disjoint from ffn1 [0,32) (A-operand of the same
    //   dispatch! round-3 bug): cat+4MiB -> abs [32,40), cat+12MiB -> abs [40,48),
    //   wt1, hbuf (both dead after W1 GEMM).
    char* p = (char*)d_ws;
    bf16* normed = (bf16*)p;  p += (size_t)MROWS * DD * 2;       // 8 MiB
    bf16* proj   = (bf16*)p;  p += (size_t)MROWS * NPROJ * 2;    // 20 MiB
    bf16* cat    = (bf16*)p;  p += (size_t)MROWS * CATD2 * 2;    // 20 MiB
    float* out1  = (float*)p; p += (size_t)MROWS * DD * 4;       // 16 MiB
    bf16* hbuf   = (bf16*)p;  p += (size_t)MROWS * DD * 2;       // 8 MiB
    bf16* wt_in  = (bf16*)p;  p += (size_t)NPROJ * DD * 2;       // 5 MiB
    bf16* wt_m0  = (bf16*)p;  p += (size_t)DD * DD * 2;          // 2 MiB
    bf16* wt_comb= (bf16*)p;  p += (size_t)DD * CATD2 * 2;       // 5 MiB
    bf16* wt1    = (bf16*)p;  p += (size_t)FFD * DD * 2;         // 8 MiB
    bf16* wt2    = (bf16*)p;  p += (size_t)DD * FFD * 2;         // 8 MiB
    bf16* wc_b   = (bf16*)p;  p += (size_t)INNERD * DD * 2;      // 1 MiB
    float* bmix2 = (float*)p; p += (size_t)DD * 4;               // 4 KiB
    bf16* ffn1   = (bf16*)d_ws;                  // alias [normed|proj|cat-head]
    float* kvsum = out1;                         // alias out1 region (attn)
    float* kvpref= kvsum  + (size_t)BH * NCH * 1024;
    float* kssum = kvpref + (size_t)BH * NCH * 1024;
    float* kspref= kssum  + (size_t)BH * NCH * 32;
    // split-K bf16 partials
    bf16*  m_p0  = (bf16*)d_out;
    bf16*  m_p1  = (bf16*)d_out + (size_t)MROWS * DD;
    bf16*  w2_p0 = (bf16*)((char*)cat + ((size_t)4  << 20));  // abs [32,40) MiB
    bf16*  w2_p1 = (bf16*)((char*)cat + ((size_t)12 << 20));  // abs [40,48) MiB
    bf16*  w2_p2 = wt1;
    bf16*  w2_p3 = hbuf;

    // 1. fused prep: LN1 + weight transposes (W_mix split-target) + bmix2 init
    prep_fused<<<MROWS + 13824 + 1, 256, 0, stream>>>(
        inputs, ln1_g, ln1_b, normed,
        W_in, wt_in, W_mix, wt_m0, wt_comb, W1, wt1, W2, wt2, b_mix, bmix2);
    // 2. prep2: cast W_c -> bf16; bmix2 += b_c @ Wm0
    prep2<<<512 + 64, 256, 0, stream>>>(W_c, wc_b, b_c, W_mix, bmix2);
    // 3. proj = normed @ W_in + b_in (bf16 out)
    gemm_mfma<0><<<dim3(MROWS/128, NPROJ/128), 256, 0, stream>>>(
        normed, DD, wt_in, DD, b_in, proj, NPROJ, DD, Part4{});
    // 4. wt_comb[:,0:512] = (Wm0^T @ W_c^T) = (W_c @ Wm0)^T  (bf16)
    gemm_mfma<5><<<dim3(DD/128, INNERD/128), 256, 0, stream>>>(
        wt_m0, DD, wc_b, DD, nullptr, wt_comb, CATD2, DD, Part4{});
    // 5. fused dwconv + attn phase A
    mid_fused<<<1024 + 512, 256, 0, stream>>>(
        normed, w_t, b_t, w_p, b_p, cat, proj, mask, kvsum, kssum);
    // 6-7. prefix + scan (scan writes cat[:,0:512))
    attn_prefix<<<132, 256, 0, stream>>>(kvsum, kssum, kvpref, kspref);
    attn_scan  <<<BH * NCH, 64, 0, stream>>>(proj, mask, kvpref, kspref, cat);
    // 8. mix split-2 bf16 partials: cat(2560) @ wt_comb
    gemm_mfma<4><<<dim3(MROWS/128, DD/128, 2), 256, 0, stream>>>(
        cat, CATD2, wt_comb, CATD2, nullptr, nullptr, DD, CATD2 / 2,
        Part4{m_p0, m_p1, nullptr, nullptr});
    // 9. out1 = (inputs + sigmoid(gate)*(P0+P1+bmix2))*mask ; hbuf = LN2(out1)
    epi_mix_ln2<<<MROWS, 256, 0, stream>>>(m_p0, m_p1, bmix2, proj, inputs,
                                           mask, ln2_g, ln2_b, out1, hbuf);
    // 10. ffn1 = gelu(hbuf @ W1 + b1)
    gemm_mfma<1><<<dim3(MROWS/128, FFD/128), 256, 0, stream>>>(
        hbuf, DD, wt1, DD, b1, ffn1, FFD, DD, Part4{});
    // 11. W2 split-4 bf16 partials (partials disjoint from ffn1!)
    gemm_mfma<4><<<dim3(MROWS/128, DD/128, 4), 256, 0, stream>>>(
        ffn1, FFD, wt2, FFD, nullptr, nullptr, DD, FFD / 4,
        Part4{w2_p0, w2_p1, w2_p2, w2_p3});
    // 12. out = (out1 + sum P + b2) * mask
    epi_w2<<<MROWS * DD / 4 / 256, 256, 0, stream>>>(out, out1, w2_p0, w2_p1,
                                                     w2_p2, w2_p3, b2, mask);
}